// Round 2
// baseline (2339.511 us; speedup 1.0000x reference)
//
#include <hip/hip_runtime.h>
#include <cstdint>
#include <cstddef>

#define FIN      128
#define HGAT_H   4
#define HGAT_C   64
#define HGAT_HC  256
#define NGRAPHS  64
#define NACT     32

// ---------------------------------------------------------------------------
// GEMM: C[M,Nc] = A[M,K] @ B[K,Nc], f32.  BM=128, BN=64, BK=32, 256 threads,
// 8x4 microtile. A staged transposed (stride 132), B stride 68 (bank-safe).
// ---------------------------------------------------------------------------
__global__ __launch_bounds__(256) void gemm_f32_kernel(
    const float* __restrict__ A, const float* __restrict__ B,
    float* __restrict__ C, int M, int K, int Nc)
{
    __shared__ float As[32 * 132];   // As[kk*132 + m], m in [0,128)
    __shared__ float Bs[32 * 68];    // Bs[kk*68 + n],  n in [0,64)

    const int t  = threadIdx.x;
    const int tx = t & 15;           // column group 0..15
    const int ty = t >> 4;           // row group    0..15
    const int m0 = blockIdx.x * 128;
    const int n0 = blockIdx.y * 64;

    float acc[8][4];
#pragma unroll
    for (int i = 0; i < 8; ++i)
#pragma unroll
        for (int j = 0; j < 4; ++j) acc[i][j] = 0.f;

    for (int k0 = 0; k0 < K; k0 += 32) {
        __syncthreads();
        // stage A (transposed): 128 rows x 32 cols
        {
            const int kk = (t & 7) * 4;
#pragma unroll
            for (int it = 0; it < 4; ++it) {
                int r  = (t >> 3) + it * 32;
                int gm = m0 + r; if (gm >= M) gm = M - 1;   // clamp; store guarded
                const float4 v = *reinterpret_cast<const float4*>(
                    &A[(size_t)gm * K + k0 + kk]);
                As[(kk + 0) * 132 + r] = v.x;
                As[(kk + 1) * 132 + r] = v.y;
                As[(kk + 2) * 132 + r] = v.z;
                As[(kk + 3) * 132 + r] = v.w;
            }
        }
        // stage B: 32 rows x 64 cols
        {
            const int col = (t & 15) * 4;
#pragma unroll
            for (int it = 0; it < 2; ++it) {
                int kk = (t >> 4) + it * 16;
                const float4 v = *reinterpret_cast<const float4*>(
                    &B[(size_t)(k0 + kk) * Nc + n0 + col]);
                *reinterpret_cast<float4*>(&Bs[kk * 68 + col]) = v;
            }
        }
        __syncthreads();

#pragma unroll
        for (int kk = 0; kk < 32; ++kk) {
            const float4 a0 = *reinterpret_cast<const float4*>(&As[kk * 132 + ty * 8]);
            const float4 a1 = *reinterpret_cast<const float4*>(&As[kk * 132 + ty * 8 + 4]);
            const float4 b  = *reinterpret_cast<const float4*>(&Bs[kk * 68 + tx * 4]);
            const float av[8] = {a0.x, a0.y, a0.z, a0.w, a1.x, a1.y, a1.z, a1.w};
#pragma unroll
            for (int i = 0; i < 8; ++i) {
                acc[i][0] += av[i] * b.x;
                acc[i][1] += av[i] * b.y;
                acc[i][2] += av[i] * b.z;
                acc[i][3] += av[i] * b.w;
            }
        }
    }

#pragma unroll
    for (int i = 0; i < 8; ++i) {
        const int gm = m0 + ty * 8 + i;
        if (gm < M) {
            float4 v = {acc[i][0], acc[i][1], acc[i][2], acc[i][3]};
            *reinterpret_cast<float4*>(&C[(size_t)gm * Nc + n0 + tx * 4]) = v;
        }
    }
}

// ---------------------------------------------------------------------------
// Per-node attention coefficients: a_src[n,h] = sum_c h[n,h,c]*att_s[h,c], etc.
// One wave per node; lane = channel.
// ---------------------------------------------------------------------------
__global__ __launch_bounds__(256) void att_coef_kernel(
    const float* __restrict__ hbuf, const float* __restrict__ att_s,
    const float* __restrict__ att_d, float* __restrict__ a_src,
    float* __restrict__ a_dst, int N)
{
    const int wave = (blockIdx.x * 256 + threadIdx.x) >> 6;
    const int lane = threadIdx.x & 63;
    if (wave >= N) return;
    const float* hrow = hbuf + (size_t)wave * HGAT_HC;
#pragma unroll
    for (int h = 0; h < HGAT_H; ++h) {
        const float v = hrow[h * 64 + lane];
        float s = v * att_s[h * 64 + lane];
        float d = v * att_d[h * 64 + lane];
#pragma unroll
        for (int off = 32; off; off >>= 1) {
            s += __shfl_xor(s, off);
            d += __shfl_xor(d, off);
        }
        if (lane == 0) {
            a_src[wave * 4 + h] = s;
            a_dst[wave * 4 + h] = d;
        }
    }
}

// ---------------------------------------------------------------------------
// Edge pass: denom[dst,h] += exp(leaky_relu(a_src[src,h]+a_dst[dst,h]))
// (no max-subtraction: |e| is small, alpha is identical after normalization)
// ---------------------------------------------------------------------------
__global__ __launch_bounds__(256) void edge_pass_kernel(
    const int* __restrict__ ei, const float* __restrict__ a_src,
    const float* __restrict__ a_dst, float* __restrict__ denom, int E, int ET)
{
    const int e = blockIdx.x * 256 + threadIdx.x;
    if (e >= ET) return;
    int s, d;
    if (e < E) { s = ei[e]; d = ei[E + e]; }
    else       { s = d = e - E; }
#pragma unroll
    for (int h = 0; h < HGAT_H; ++h) {
        float ee = a_src[s * 4 + h] + a_dst[d * 4 + h];
        ee = ee > 0.f ? ee : 0.2f * ee;
        atomicAdd(&denom[d * 4 + h], expf(ee));
    }
}

// ---------------------------------------------------------------------------
// Aggregate: out[dst, h*64+c] += h[src, h*64+c] * alpha(e,h).  Wave per edge,
// lane = channel within head; alpha recomputed on the fly (no p buffer).
// ---------------------------------------------------------------------------
__global__ __launch_bounds__(256) void aggregate_kernel(
    const int* __restrict__ ei, const float* __restrict__ hbuf,
    const float* __restrict__ a_src, const float* __restrict__ a_dst,
    const float* __restrict__ denom, float* __restrict__ out, int E, int ET)
{
    const int e    = (blockIdx.x * 256 + threadIdx.x) >> 6;
    const int lane = threadIdx.x & 63;
    if (e >= ET) return;
    int s, d;
    if (e < E) { s = ei[e]; d = ei[E + e]; }
    else       { s = d = e - E; }
    const float* hrow = hbuf + (size_t)s * HGAT_HC;
    float* orow = out + (size_t)d * HGAT_HC;
#pragma unroll
    for (int h = 0; h < HGAT_H; ++h) {
        float ee = a_src[s * 4 + h] + a_dst[d * 4 + h];
        ee = ee > 0.f ? ee : 0.2f * ee;
        const float alpha = expf(ee) / denom[d * 4 + h];
        atomicAdd(&orow[h * 64 + lane], hrow[h * 64 + lane] * alpha);
    }
}

// ---------------------------------------------------------------------------
// out = elu(out + bias[c]) in-place over [N,256], float4 per thread.
// ---------------------------------------------------------------------------
__global__ __launch_bounds__(256) void bias_elu_kernel(
    float* __restrict__ buf, const float* __restrict__ bias, size_t total4)
{
    const size_t i = (size_t)blockIdx.x * 256 + threadIdx.x;
    if (i >= total4) return;
    float4 v = reinterpret_cast<float4*>(buf)[i];
    const int c = (int)((i * 4) & (HGAT_HC - 1));
    v.x += bias[c + 0]; v.y += bias[c + 1]; v.z += bias[c + 2]; v.w += bias[c + 3];
    v.x = v.x > 0.f ? v.x : expm1f(v.x);
    v.y = v.y > 0.f ? v.y : expm1f(v.y);
    v.z = v.z > 0.f ? v.z : expm1f(v.z);
    v.w = v.w > 0.f ? v.w : expm1f(v.w);
    reinterpret_cast<float4*>(buf)[i] = v;
}

// ---------------------------------------------------------------------------
// Head mean + bias + ELU: hfin[n,c] = elu(mean_h agg[n,h*64+c] + b2[c])
// ---------------------------------------------------------------------------
__global__ __launch_bounds__(256) void head_mean_kernel(
    const float* __restrict__ agg, const float* __restrict__ b2,
    float* __restrict__ hfin, int N)
{
    const int idx = blockIdx.x * 256 + threadIdx.x;
    if (idx >= N * HGAT_C) return;
    const int n = idx >> 6, c = idx & 63;
    const float* row = agg + (size_t)n * HGAT_HC;
    float v = 0.25f * (row[c] + row[64 + c] + row[128 + c] + row[192 + c]) + b2[c];
    hfin[idx] = v > 0.f ? v : expm1f(v);
}

// ---------------------------------------------------------------------------
// Per-graph mean pool (sums + counts). Wave per node, lane = channel.
// ---------------------------------------------------------------------------
__global__ __launch_bounds__(256) void pool_kernel(
    const float* __restrict__ hfin, const int* __restrict__ batch,
    float* __restrict__ pooled, float* __restrict__ cnt, int N)
{
    const int n    = (blockIdx.x * 256 + threadIdx.x) >> 6;
    const int lane = threadIdx.x & 63;
    if (n >= N) return;
    const int g = batch[n];
    atomicAdd(&pooled[g * 64 + lane], hfin[(size_t)n * 64 + lane]);
    if (lane == 0) atomicAdd(&cnt[g], 1.0f);
}

// ---------------------------------------------------------------------------
// Final: out[g,a] = (pooled[g,:]/cnt[g]) @ Wa + ba
// ---------------------------------------------------------------------------
__global__ __launch_bounds__(256) void final_kernel(
    const float* __restrict__ pooled, const float* __restrict__ cnt,
    const float* __restrict__ Wa, const float* __restrict__ ba,
    float* __restrict__ out)
{
    const int tid = blockIdx.x * 256 + threadIdx.x;
    if (tid >= NGRAPHS * NACT) return;
    const int g = tid >> 5, a = tid & 31;
    const float inv = 1.0f / fmaxf(cnt[g], 1.0f);
    float s = 0.f;
#pragma unroll
    for (int c = 0; c < HGAT_C; ++c)
        s += pooled[g * 64 + c] * inv * Wa[c * NACT + a];
    out[tid] = s + ba[a];
}

// ---------------------------------------------------------------------------
extern "C" void kernel_launch(void* const* d_in, const int* in_sizes, int n_in,
                              void* d_out, int out_size, void* d_ws, size_t ws_size,
                              hipStream_t stream)
{
    const float* x     = (const float*)d_in[0];
    const int*   ei    = (const int*)d_in[1];     // int32 (harness convention)
    const int*   batch = (const int*)d_in[2];     // int32
    const float* W1    = (const float*)d_in[5];
    const float* as1   = (const float*)d_in[6];
    const float* ad1   = (const float*)d_in[7];
    const float* b1    = (const float*)d_in[8];
    const float* W2    = (const float*)d_in[9];
    const float* as2   = (const float*)d_in[10];
    const float* ad2   = (const float*)d_in[11];
    const float* b2    = (const float*)d_in[12];
    const float* Wa    = (const float*)d_in[13];
    const float* ba    = (const float*)d_in[14];

    const int N  = in_sizes[0] / FIN;
    const int E  = in_sizes[1] / 2;
    const int ET = E + N;

    char* ws = (char*)d_ws;
    size_t off = 0;
    auto alloc = [&](size_t bytes) -> void* {
        void* p = ws + off;
        off += (bytes + 255) & ~(size_t)255;
        return p;
    };
    float* h1    = (float*)alloc((size_t)N * HGAT_HC * 4);  // projections (both layers)
    float* bufB  = (float*)alloc((size_t)N * HGAT_HC * 4);  // agg accum / hpost1
    float* a_src = (float*)alloc((size_t)N * 4 * 4);
    float* a_dst = (float*)alloc((size_t)N * 4 * 4);
    float* denom = (float*)alloc((size_t)N * 4 * 4);
    float* pooled= (float*)alloc(NGRAPHS * HGAT_C * 4);
    float* cnt   = (float*)alloc(NGRAPHS * 4);
    float* hfin  = h1;   // reuse: h (projections) dead once layer-2 agg done
    (void)ws_size; (void)n_in; (void)out_size;

    const dim3 gemmGrid((N + 127) / 128, HGAT_HC / 64);
    const int edgeBlocks = (ET + 255) / 256;
    const int edgeWaveBlocks = (ET + 3) / 4;
    const int nodeWaveBlocks = (N + 3) / 4;

    // ---------------- layer 1 ----------------
    hipMemsetAsync(bufB, 0, (size_t)N * HGAT_HC * 4, stream);
    hipMemsetAsync(denom, 0, (size_t)N * 4 * 4, stream);
    gemm_f32_kernel<<<gemmGrid, 256, 0, stream>>>(x, W1, h1, N, FIN, HGAT_HC);
    att_coef_kernel<<<nodeWaveBlocks, 256, 0, stream>>>(h1, as1, ad1, a_src, a_dst, N);
    edge_pass_kernel<<<edgeBlocks, 256, 0, stream>>>(ei, a_src, a_dst, denom, E, ET);
    aggregate_kernel<<<edgeWaveBlocks, 256, 0, stream>>>(ei, h1, a_src, a_dst, denom, bufB, E, ET);
    bias_elu_kernel<<<(int)(((size_t)N * HGAT_HC / 4 + 255) / 256), 256, 0, stream>>>(
        bufB, b1, (size_t)N * HGAT_HC / 4);

    // ---------------- layer 2 ----------------
    gemm_f32_kernel<<<gemmGrid, 256, 0, stream>>>(bufB, W2, h1, N, HGAT_HC, HGAT_HC);
    att_coef_kernel<<<nodeWaveBlocks, 256, 0, stream>>>(h1, as2, ad2, a_src, a_dst, N);
    hipMemsetAsync(bufB, 0, (size_t)N * HGAT_HC * 4, stream);
    hipMemsetAsync(denom, 0, (size_t)N * 4 * 4, stream);
    edge_pass_kernel<<<edgeBlocks, 256, 0, stream>>>(ei, a_src, a_dst, denom, E, ET);
    aggregate_kernel<<<edgeWaveBlocks, 256, 0, stream>>>(ei, h1, a_src, a_dst, denom, bufB, E, ET);
    // h1 (projections) now dead -> hfin aliases it
    head_mean_kernel<<<(N * HGAT_C + 255) / 256, 256, 0, stream>>>(bufB, b2, hfin, N);

    // ---------------- pool + final ----------------
    hipMemsetAsync(pooled, 0, NGRAPHS * HGAT_C * 4, stream);
    hipMemsetAsync(cnt, 0, NGRAPHS * 4, stream);
    pool_kernel<<<nodeWaveBlocks, 256, 0, stream>>>(hfin, batch, pooled, cnt, N);
    final_kernel<<<(NGRAPHS * NACT + 255) / 256, 256, 0, stream>>>(
        pooled, cnt, Wa, ba, (float*)d_out);
}

// Round 3
// 1042.997 us; speedup vs baseline: 2.2431x; 2.2431x over previous
//
#include <hip/hip_runtime.h>
#include <cstdint>
#include <cstddef>

#define FIN      128
#define HGAT_H   4
#define HGAT_C   64
#define HGAT_HC  256
#define NGRAPHS  64
#define NACT     32

// ---------------------------------------------------------------------------
// GEMM: C[M,Nc] = A[M,K] @ B[K,Nc], f32.  BM=128, BN=64, BK=32, 256 threads,
// 8x4 microtile. A staged transposed (stride 132), B stride 68 (bank-safe).
// ---------------------------------------------------------------------------
__global__ __launch_bounds__(256) void gemm_f32_kernel(
    const float* __restrict__ A, const float* __restrict__ B,
    float* __restrict__ C, int M, int K, int Nc)
{
    __shared__ float As[32 * 132];   // As[kk*132 + m], m in [0,128)
    __shared__ float Bs[32 * 68];    // Bs[kk*68 + n],  n in [0,64)

    const int t  = threadIdx.x;
    const int tx = t & 15;           // column group 0..15
    const int ty = t >> 4;           // row group    0..15
    const int m0 = blockIdx.x * 128;
    const int n0 = blockIdx.y * 64;

    float acc[8][4];
#pragma unroll
    for (int i = 0; i < 8; ++i)
#pragma unroll
        for (int j = 0; j < 4; ++j) acc[i][j] = 0.f;

    for (int k0 = 0; k0 < K; k0 += 32) {
        __syncthreads();
        {
            const int kk = (t & 7) * 4;
#pragma unroll
            for (int it = 0; it < 4; ++it) {
                int r  = (t >> 3) + it * 32;
                int gm = m0 + r; if (gm >= M) gm = M - 1;
                const float4 v = *reinterpret_cast<const float4*>(
                    &A[(size_t)gm * K + k0 + kk]);
                As[(kk + 0) * 132 + r] = v.x;
                As[(kk + 1) * 132 + r] = v.y;
                As[(kk + 2) * 132 + r] = v.z;
                As[(kk + 3) * 132 + r] = v.w;
            }
        }
        {
            const int col = (t & 15) * 4;
#pragma unroll
            for (int it = 0; it < 2; ++it) {
                int kk = (t >> 4) + it * 16;
                const float4 v = *reinterpret_cast<const float4*>(
                    &B[(size_t)(k0 + kk) * Nc + n0 + col]);
                *reinterpret_cast<float4*>(&Bs[kk * 68 + col]) = v;
            }
        }
        __syncthreads();

#pragma unroll
        for (int kk = 0; kk < 32; ++kk) {
            const float4 a0 = *reinterpret_cast<const float4*>(&As[kk * 132 + ty * 8]);
            const float4 a1 = *reinterpret_cast<const float4*>(&As[kk * 132 + ty * 8 + 4]);
            const float4 b  = *reinterpret_cast<const float4*>(&Bs[kk * 68 + tx * 4]);
            const float av[8] = {a0.x, a0.y, a0.z, a0.w, a1.x, a1.y, a1.z, a1.w};
#pragma unroll
            for (int i = 0; i < 8; ++i) {
                acc[i][0] += av[i] * b.x;
                acc[i][1] += av[i] * b.y;
                acc[i][2] += av[i] * b.z;
                acc[i][3] += av[i] * b.w;
            }
        }
    }

#pragma unroll
    for (int i = 0; i < 8; ++i) {
        const int gm = m0 + ty * 8 + i;
        if (gm < M) {
            float4 v = {acc[i][0], acc[i][1], acc[i][2], acc[i][3]};
            *reinterpret_cast<float4*>(&C[(size_t)gm * Nc + n0 + tx * 4]) = v;
        }
    }
}

// ---------------------------------------------------------------------------
// Per-node attention coefficients: a_src[n,h] = sum_c h[n,h,c]*att_s[h,c].
// One wave per node; lane = channel.
// ---------------------------------------------------------------------------
__global__ __launch_bounds__(256) void att_coef_kernel(
    const float* __restrict__ hbuf, const float* __restrict__ att_s,
    const float* __restrict__ att_d, float* __restrict__ a_src,
    float* __restrict__ a_dst, int N)
{
    const int wave = (blockIdx.x * 256 + threadIdx.x) >> 6;
    const int lane = threadIdx.x & 63;
    if (wave >= N) return;
    const float* hrow = hbuf + (size_t)wave * HGAT_HC;
#pragma unroll
    for (int h = 0; h < HGAT_H; ++h) {
        const float v = hrow[h * 64 + lane];
        float s = v * att_s[h * 64 + lane];
        float d = v * att_d[h * 64 + lane];
#pragma unroll
        for (int off = 32; off; off >>= 1) {
            s += __shfl_xor(s, off);
            d += __shfl_xor(d, off);
        }
        if (lane == 0) {
            a_src[wave * 4 + h] = s;
            a_dst[wave * 4 + h] = d;
        }
    }
}

// ---------------------------------------------------------------------------
// CSR build: degree count, single-block scan, cursor fill.
// ---------------------------------------------------------------------------
__global__ __launch_bounds__(256) void count_deg_kernel(
    const int* __restrict__ ei, int* __restrict__ deg, int E)
{
    const int e = blockIdx.x * 256 + threadIdx.x;
    if (e < E) atomicAdd(&deg[ei[E + e]], 1);
}

__global__ __launch_bounds__(1024) void scan_kernel(
    const int* __restrict__ deg, int* __restrict__ rowptr, int N)
{
    __shared__ int sm[1024];
    const int tid = threadIdx.x;
    const int chunk = (N + 1023) >> 10;
    const int base = tid * chunk;
    int s = 0;
    for (int i = 0; i < chunk; ++i) {
        const int idx = base + i;
        if (idx < N) s += deg[idx];
    }
    sm[tid] = s;
    __syncthreads();
    for (int off = 1; off < 1024; off <<= 1) {
        int v = (tid >= off) ? sm[tid - off] : 0;
        __syncthreads();
        sm[tid] += v;
        __syncthreads();
    }
    int run = (tid == 0) ? 0 : sm[tid - 1];
    for (int i = 0; i < chunk; ++i) {
        const int idx = base + i;
        if (idx < N) { rowptr[idx] = run; run += deg[idx]; }
    }
    if (tid == 1023) rowptr[N] = sm[1023];
}

__global__ __launch_bounds__(256) void fill_csr_kernel(
    const int* __restrict__ ei, int* __restrict__ cursor,
    int* __restrict__ colsrc, int E)
{
    const int e = blockIdx.x * 256 + threadIdx.x;
    if (e >= E) return;
    const int d = ei[E + e];
    const int pos = atomicAdd(&cursor[d], 1);
    colsrc[pos] = ei[e];
}

// ---------------------------------------------------------------------------
// CSR aggregate, wave per dst node. lane -> 4 channels (float4), head=lane>>4.
// Accumulates sum_e w_e*h[src] and sum_e w_e in registers (self-loop inline),
// then writes the normalized, biased, ELU'd output once.
// MODE 0: concat -> out[N,256].  MODE 1: head-mean -> out[N,64].
// ---------------------------------------------------------------------------
template <int MODE>
__global__ __launch_bounds__(256) void aggregate_csr_kernel(
    const int* __restrict__ rowptr, const int* __restrict__ colsrc,
    const float* __restrict__ hbuf, const float* __restrict__ a_src,
    const float* __restrict__ a_dst, const float* __restrict__ bias,
    float* __restrict__ out, int N)
{
    const int d    = (blockIdx.x * 256 + threadIdx.x) >> 6;
    const int lane = threadIdx.x & 63;
    if (d >= N) return;
    const int h  = lane >> 4;
    const int c0 = lane * 4;
    const float ad = a_dst[d * 4 + h];

    float4 acc = {0.f, 0.f, 0.f, 0.f};
    float  den = 0.f;

    const int beg = rowptr[d], end = rowptr[d + 1];
    for (int i = beg; i < end; ++i) {
        const int s = colsrc[i];
        float ee = a_src[s * 4 + h] + ad;
        ee = ee > 0.f ? ee : 0.2f * ee;
        const float w = expf(ee);
        const float4 hv = *reinterpret_cast<const float4*>(
            &hbuf[(size_t)s * HGAT_HC + c0]);
        acc.x += w * hv.x; acc.y += w * hv.y;
        acc.z += w * hv.z; acc.w += w * hv.w;
        den += w;
    }
    {   // self loop
        float ee = a_src[d * 4 + h] + ad;
        ee = ee > 0.f ? ee : 0.2f * ee;
        const float w = expf(ee);
        const float4 hv = *reinterpret_cast<const float4*>(
            &hbuf[(size_t)d * HGAT_HC + c0]);
        acc.x += w * hv.x; acc.y += w * hv.y;
        acc.z += w * hv.z; acc.w += w * hv.w;
        den += w;
    }

    const float inv = 1.0f / den;
    float4 v = {acc.x * inv, acc.y * inv, acc.z * inv, acc.w * inv};

    if (MODE == 0) {
        v.x += bias[c0 + 0]; v.y += bias[c0 + 1];
        v.z += bias[c0 + 2]; v.w += bias[c0 + 3];
        v.x = v.x > 0.f ? v.x : expm1f(v.x);
        v.y = v.y > 0.f ? v.y : expm1f(v.y);
        v.z = v.z > 0.f ? v.z : expm1f(v.z);
        v.w = v.w > 0.f ? v.w : expm1f(v.w);
        *reinterpret_cast<float4*>(&out[(size_t)d * HGAT_HC + c0]) = v;
    } else {
        // reduce across heads: lanes {l, l^16, l^32, l^48} hold same channel
        v.x += __shfl_xor(v.x, 16); v.x += __shfl_xor(v.x, 32);
        v.y += __shfl_xor(v.y, 16); v.y += __shfl_xor(v.y, 32);
        v.z += __shfl_xor(v.z, 16); v.z += __shfl_xor(v.z, 32);
        v.w += __shfl_xor(v.w, 16); v.w += __shfl_xor(v.w, 32);
        if (lane < 16) {
            const int c = lane * 4;
            float4 r;
            r.x = 0.25f * v.x + bias[c + 0];
            r.y = 0.25f * v.y + bias[c + 1];
            r.z = 0.25f * v.z + bias[c + 2];
            r.w = 0.25f * v.w + bias[c + 3];
            r.x = r.x > 0.f ? r.x : expm1f(r.x);
            r.y = r.y > 0.f ? r.y : expm1f(r.y);
            r.z = r.z > 0.f ? r.z : expm1f(r.z);
            r.w = r.w > 0.f ? r.w : expm1f(r.w);
            *reinterpret_cast<float4*>(&out[(size_t)d * HGAT_C + c]) = r;
        }
    }
}

// ---------------------------------------------------------------------------
// Per-graph mean pool (sums + counts). Wave per node, lane = channel.
// ---------------------------------------------------------------------------
__global__ __launch_bounds__(256) void pool_kernel(
    const float* __restrict__ hfin, const int* __restrict__ batch,
    float* __restrict__ pooled, float* __restrict__ cnt, int N)
{
    const int n    = (blockIdx.x * 256 + threadIdx.x) >> 6;
    const int lane = threadIdx.x & 63;
    if (n >= N) return;
    const int g = batch[n];
    atomicAdd(&pooled[g * 64 + lane], hfin[(size_t)n * 64 + lane]);
    if (lane == 0) atomicAdd(&cnt[g], 1.0f);
}

// ---------------------------------------------------------------------------
// Final: out[g,a] = (pooled[g,:]/cnt[g]) @ Wa + ba
// ---------------------------------------------------------------------------
__global__ __launch_bounds__(256) void final_kernel(
    const float* __restrict__ pooled, const float* __restrict__ cnt,
    const float* __restrict__ Wa, const float* __restrict__ ba,
    float* __restrict__ out)
{
    const int tid = blockIdx.x * 256 + threadIdx.x;
    if (tid >= NGRAPHS * NACT) return;
    const int g = tid >> 5, a = tid & 31;
    const float inv = 1.0f / fmaxf(cnt[g], 1.0f);
    float s = 0.f;
#pragma unroll
    for (int c = 0; c < HGAT_C; ++c)
        s += pooled[g * 64 + c] * inv * Wa[c * NACT + a];
    out[tid] = s + ba[a];
}

// ---------------------------------------------------------------------------
extern "C" void kernel_launch(void* const* d_in, const int* in_sizes, int n_in,
                              void* d_out, int out_size, void* d_ws, size_t ws_size,
                              hipStream_t stream)
{
    const float* x     = (const float*)d_in[0];
    const int*   ei    = (const int*)d_in[1];
    const int*   batch = (const int*)d_in[2];
    const float* W1    = (const float*)d_in[5];
    const float* as1   = (const float*)d_in[6];
    const float* ad1   = (const float*)d_in[7];
    const float* b1    = (const float*)d_in[8];
    const float* W2    = (const float*)d_in[9];
    const float* as2   = (const float*)d_in[10];
    const float* ad2   = (const float*)d_in[11];
    const float* b2    = (const float*)d_in[12];
    const float* Wa    = (const float*)d_in[13];
    const float* ba    = (const float*)d_in[14];

    const int N = in_sizes[0] / FIN;
    const int E = in_sizes[1] / 2;

    char* ws = (char*)d_ws;
    size_t off = 0;
    auto alloc = [&](size_t bytes) -> void* {
        void* p = ws + off;
        off += (bytes + 255) & ~(size_t)255;
        return p;
    };
    float* h1     = (float*)alloc((size_t)N * HGAT_HC * 4);  // projections
    float* hpost  = (float*)alloc((size_t)N * HGAT_HC * 4);  // L1 out / hfin
    float* a_src  = (float*)alloc((size_t)N * 4 * 4);
    float* a_dst  = (float*)alloc((size_t)N * 4 * 4);
    int*   rowptr = (int*)alloc((size_t)(N + 1) * 4);
    int*   colsrc = (int*)alloc((size_t)E * 4);
    int*   deg    = (int*)alloc((size_t)N * 4);
    int*   cursor = (int*)alloc((size_t)N * 4);
    float* pooled = (float*)alloc(NGRAPHS * HGAT_C * 4);
    float* cnt    = (float*)alloc(NGRAPHS * 4);
    float* hfin   = hpost;   // reuse: hpost dead after gemm2 reads it
    (void)ws_size; (void)n_in; (void)out_size;

    const dim3 gemmGrid((N + 127) / 128, HGAT_HC / 64);
    const int edgeBlocks     = (E + 255) / 256;
    const int nodeWaveBlocks = (N + 3) / 4;

    // ---------------- CSR build (shared by both layers) ----------------
    hipMemsetAsync(deg, 0, (size_t)N * 4, stream);
    count_deg_kernel<<<edgeBlocks, 256, 0, stream>>>(ei, deg, E);
    scan_kernel<<<1, 1024, 0, stream>>>(deg, rowptr, N);
    hipMemcpyAsync(cursor, rowptr, (size_t)N * 4, hipMemcpyDeviceToDevice, stream);
    fill_csr_kernel<<<edgeBlocks, 256, 0, stream>>>(ei, cursor, colsrc, E);

    // ---------------- layer 1 ----------------
    gemm_f32_kernel<<<gemmGrid, 256, 0, stream>>>(x, W1, h1, N, FIN, HGAT_HC);
    att_coef_kernel<<<nodeWaveBlocks, 256, 0, stream>>>(h1, as1, ad1, a_src, a_dst, N);
    aggregate_csr_kernel<0><<<nodeWaveBlocks, 256, 0, stream>>>(
        rowptr, colsrc, h1, a_src, a_dst, b1, hpost, N);

    // ---------------- layer 2 ----------------
    gemm_f32_kernel<<<gemmGrid, 256, 0, stream>>>(hpost, W2, h1, N, HGAT_HC, HGAT_HC);
    att_coef_kernel<<<nodeWaveBlocks, 256, 0, stream>>>(h1, as2, ad2, a_src, a_dst, N);
    aggregate_csr_kernel<1><<<nodeWaveBlocks, 256, 0, stream>>>(
        rowptr, colsrc, h1, a_src, a_dst, b2, hfin, N);

    // ---------------- pool + final ----------------
    hipMemsetAsync(pooled, 0, NGRAPHS * HGAT_C * 4, stream);
    hipMemsetAsync(cnt, 0, NGRAPHS * 4, stream);
    pool_kernel<<<nodeWaveBlocks, 256, 0, stream>>>(hfin, batch, pooled, cnt, N);
    final_kernel<<<(NGRAPHS * NACT + 255) / 256, 256, 0, stream>>>(
        pooled, cnt, Wa, ba, (float*)d_out);
}

// Round 4
// 704.072 us; speedup vs baseline: 3.3228x; 1.4814x over previous
//
#include <hip/hip_runtime.h>
#include <cstdint>
#include <cstddef>

#define FIN      128
#define HGAT_H   4
#define HGAT_C   64
#define HGAT_HC  256
#define NGRAPHS  64
#define NACT     32

// ---------------------------------------------------------------------------
// GEMM: C[M,Nc] = A[M,K] @ B[K,Nc], f32.  BM=128, BN=64, BK=32, 256 threads,
// 8x4 microtile. A staged transposed (stride 132), B stride 68 (bank-safe).
// ---------------------------------------------------------------------------
__global__ __launch_bounds__(256) void gemm_f32_kernel(
    const float* __restrict__ A, const float* __restrict__ B,
    float* __restrict__ C, int M, int K, int Nc)
{
    __shared__ float As[32 * 132];   // As[kk*132 + m], m in [0,128)
    __shared__ float Bs[32 * 68];    // Bs[kk*68 + n],  n in [0,64)

    const int t  = threadIdx.x;
    const int tx = t & 15;           // column group 0..15
    const int ty = t >> 4;           // row group    0..15
    const int m0 = blockIdx.x * 128;
    const int n0 = blockIdx.y * 64;

    float acc[8][4];
#pragma unroll
    for (int i = 0; i < 8; ++i)
#pragma unroll
        for (int j = 0; j < 4; ++j) acc[i][j] = 0.f;

    for (int k0 = 0; k0 < K; k0 += 32) {
        __syncthreads();
        {
            const int kk = (t & 7) * 4;
#pragma unroll
            for (int it = 0; it < 4; ++it) {
                int r  = (t >> 3) + it * 32;
                int gm = m0 + r; if (gm >= M) gm = M - 1;
                const float4 v = *reinterpret_cast<const float4*>(
                    &A[(size_t)gm * K + k0 + kk]);
                As[(kk + 0) * 132 + r] = v.x;
                As[(kk + 1) * 132 + r] = v.y;
                As[(kk + 2) * 132 + r] = v.z;
                As[(kk + 3) * 132 + r] = v.w;
            }
        }
        {
            const int col = (t & 15) * 4;
#pragma unroll
            for (int it = 0; it < 2; ++it) {
                int kk = (t >> 4) + it * 16;
                const float4 v = *reinterpret_cast<const float4*>(
                    &B[(size_t)(k0 + kk) * Nc + n0 + col]);
                *reinterpret_cast<float4*>(&Bs[kk * 68 + col]) = v;
            }
        }
        __syncthreads();

#pragma unroll
        for (int kk = 0; kk < 32; ++kk) {
            const float4 a0 = *reinterpret_cast<const float4*>(&As[kk * 132 + ty * 8]);
            const float4 a1 = *reinterpret_cast<const float4*>(&As[kk * 132 + ty * 8 + 4]);
            const float4 b  = *reinterpret_cast<const float4*>(&Bs[kk * 68 + tx * 4]);
            const float av[8] = {a0.x, a0.y, a0.z, a0.w, a1.x, a1.y, a1.z, a1.w};
#pragma unroll
            for (int i = 0; i < 8; ++i) {
                acc[i][0] += av[i] * b.x;
                acc[i][1] += av[i] * b.y;
                acc[i][2] += av[i] * b.z;
                acc[i][3] += av[i] * b.w;
            }
        }
    }

#pragma unroll
    for (int i = 0; i < 8; ++i) {
        const int gm = m0 + ty * 8 + i;
        if (gm < M) {
            float4 v = {acc[i][0], acc[i][1], acc[i][2], acc[i][3]};
            *reinterpret_cast<float4*>(&C[(size_t)gm * Nc + n0 + tx * 4]) = v;
        }
    }
}

// ---------------------------------------------------------------------------
// Per-node attention coefficients: a_src[n,h] = sum_c h[n,h,c]*att_s[h,c].
// One wave per node; lane = channel.
// ---------------------------------------------------------------------------
__global__ __launch_bounds__(256) void att_coef_kernel(
    const float* __restrict__ hbuf, const float* __restrict__ att_s,
    const float* __restrict__ att_d, float* __restrict__ a_src,
    float* __restrict__ a_dst, int N)
{
    const int wave = (blockIdx.x * 256 + threadIdx.x) >> 6;
    const int lane = threadIdx.x & 63;
    if (wave >= N) return;
    const float* hrow = hbuf + (size_t)wave * HGAT_HC;
#pragma unroll
    for (int h = 0; h < HGAT_H; ++h) {
        const float v = hrow[h * 64 + lane];
        float s = v * att_s[h * 64 + lane];
        float d = v * att_d[h * 64 + lane];
#pragma unroll
        for (int off = 32; off; off >>= 1) {
            s += __shfl_xor(s, off);
            d += __shfl_xor(d, off);
        }
        if (lane == 0) {
            a_src[wave * 4 + h] = s;
            a_dst[wave * 4 + h] = d;
        }
    }
}

// ---------------------------------------------------------------------------
// CSR build: degree count, single-block scan, cursor fill.
// ---------------------------------------------------------------------------
__global__ __launch_bounds__(256) void count_deg_kernel(
    const int* __restrict__ ei, int* __restrict__ deg, int E)
{
    const int e = blockIdx.x * 256 + threadIdx.x;
    if (e < E) atomicAdd(&deg[ei[E + e]], 1);
}

__global__ __launch_bounds__(1024) void scan_kernel(
    const int* __restrict__ deg, int* __restrict__ rowptr, int N)
{
    __shared__ int sm[1024];
    const int tid = threadIdx.x;
    const int chunk = (N + 1023) >> 10;
    const int base = tid * chunk;
    int s = 0;
    for (int i = 0; i < chunk; ++i) {
        const int idx = base + i;
        if (idx < N) s += deg[idx];
    }
    sm[tid] = s;
    __syncthreads();
    for (int off = 1; off < 1024; off <<= 1) {
        int v = (tid >= off) ? sm[tid - off] : 0;
        __syncthreads();
        sm[tid] += v;
        __syncthreads();
    }
    int run = (tid == 0) ? 0 : sm[tid - 1];
    for (int i = 0; i < chunk; ++i) {
        const int idx = base + i;
        if (idx < N) { rowptr[idx] = run; run += deg[idx]; }
    }
    if (tid == 1023) rowptr[N] = sm[1023];
}

__global__ __launch_bounds__(256) void fill_csr_kernel(
    const int* __restrict__ ei, int* __restrict__ cursor,
    int* __restrict__ colsrc, int E)
{
    const int e = blockIdx.x * 256 + threadIdx.x;
    if (e >= E) return;
    const int d = ei[E + e];
    const int pos = atomicAdd(&cursor[d], 1);
    colsrc[pos] = ei[e];
}

// ---------------------------------------------------------------------------
// CSR aggregate, wave per dst node. lane -> 4 channels (float4), head=lane>>4.
// MODE 0: concat -> out[N,256].  MODE 1: head-mean -> out[N,64].
// ---------------------------------------------------------------------------
template <int MODE>
__global__ __launch_bounds__(256) void aggregate_csr_kernel(
    const int* __restrict__ rowptr, const int* __restrict__ colsrc,
    const float* __restrict__ hbuf, const float* __restrict__ a_src,
    const float* __restrict__ a_dst, const float* __restrict__ bias,
    float* __restrict__ out, int N)
{
    const int d    = (blockIdx.x * 256 + threadIdx.x) >> 6;
    const int lane = threadIdx.x & 63;
    if (d >= N) return;
    const int h  = lane >> 4;
    const int c0 = lane * 4;
    const float ad = a_dst[d * 4 + h];

    float4 acc = {0.f, 0.f, 0.f, 0.f};
    float  den = 0.f;

    const int beg = rowptr[d], end = rowptr[d + 1];
    for (int i = beg; i < end; ++i) {
        const int s = colsrc[i];
        float ee = a_src[s * 4 + h] + ad;
        ee = ee > 0.f ? ee : 0.2f * ee;
        const float w = expf(ee);
        const float4 hv = *reinterpret_cast<const float4*>(
            &hbuf[(size_t)s * HGAT_HC + c0]);
        acc.x += w * hv.x; acc.y += w * hv.y;
        acc.z += w * hv.z; acc.w += w * hv.w;
        den += w;
    }
    {   // self loop
        float ee = a_src[d * 4 + h] + ad;
        ee = ee > 0.f ? ee : 0.2f * ee;
        const float w = expf(ee);
        const float4 hv = *reinterpret_cast<const float4*>(
            &hbuf[(size_t)d * HGAT_HC + c0]);
        acc.x += w * hv.x; acc.y += w * hv.y;
        acc.z += w * hv.z; acc.w += w * hv.w;
        den += w;
    }

    const float inv = 1.0f / den;
    float4 v = {acc.x * inv, acc.y * inv, acc.z * inv, acc.w * inv};

    if (MODE == 0) {
        v.x += bias[c0 + 0]; v.y += bias[c0 + 1];
        v.z += bias[c0 + 2]; v.w += bias[c0 + 3];
        v.x = v.x > 0.f ? v.x : expm1f(v.x);
        v.y = v.y > 0.f ? v.y : expm1f(v.y);
        v.z = v.z > 0.f ? v.z : expm1f(v.z);
        v.w = v.w > 0.f ? v.w : expm1f(v.w);
        *reinterpret_cast<float4*>(&out[(size_t)d * HGAT_HC + c0]) = v;
    } else {
        // reduce across heads: lanes {l, l^16, l^32, l^48} hold same channel
        v.x += __shfl_xor(v.x, 16); v.x += __shfl_xor(v.x, 32);
        v.y += __shfl_xor(v.y, 16); v.y += __shfl_xor(v.y, 32);
        v.z += __shfl_xor(v.z, 16); v.z += __shfl_xor(v.z, 32);
        v.w += __shfl_xor(v.w, 16); v.w += __shfl_xor(v.w, 32);
        if (lane < 16) {
            const int c = lane * 4;
            float4 r;
            r.x = 0.25f * v.x + bias[c + 0];
            r.y = 0.25f * v.y + bias[c + 1];
            r.z = 0.25f * v.z + bias[c + 2];
            r.w = 0.25f * v.w + bias[c + 3];
            r.x = r.x > 0.f ? r.x : expm1f(r.x);
            r.y = r.y > 0.f ? r.y : expm1f(r.y);
            r.z = r.z > 0.f ? r.z : expm1f(r.z);
            r.w = r.w > 0.f ? r.w : expm1f(r.w);
            *reinterpret_cast<float4*>(&out[(size_t)d * HGAT_C + c]) = r;
        }
    }
}

// ---------------------------------------------------------------------------
// Segmented mean pool: batch is SORTED, so graph g owns a contiguous node
// range. One block per graph; binary-search the range; register accumulate;
// LDS reduce; single write. No atomics.
// ---------------------------------------------------------------------------
__global__ __launch_bounds__(256) void pool_seg_kernel(
    const float* __restrict__ hfin, const int* __restrict__ batch,
    float* __restrict__ pooled, int N)
{
    const int g   = blockIdx.x;
    const int t   = threadIdx.x;
    const int c   = t & 63;     // channel
    const int sub = t >> 6;     // 0..3 node subgroup

    auto lower = [&](int key) {
        int lo = 0, hi = N;
        while (lo < hi) {
            const int mid = (lo + hi) >> 1;
            if (batch[mid] < key) lo = mid + 1; else hi = mid;
        }
        return lo;
    };
    const int beg = lower(g), end = lower(g + 1);

    float s = 0.f;
    for (int n = beg + sub; n < end; n += 4)
        s += hfin[(size_t)n * HGAT_C + c];

    __shared__ float sm[256];
    sm[t] = s;
    __syncthreads();
    if (sub == 0) {
        const float tot = sm[c] + sm[64 + c] + sm[128 + c] + sm[192 + c];
        const float inv = 1.0f / fmaxf((float)(end - beg), 1.0f);
        pooled[g * HGAT_C + c] = tot * inv;
    }
}

// ---------------------------------------------------------------------------
// Final: out[g,a] = pooled[g,:] @ Wa + ba   (pooled already mean)
// ---------------------------------------------------------------------------
__global__ __launch_bounds__(256) void final_kernel(
    const float* __restrict__ pooled, const float* __restrict__ Wa,
    const float* __restrict__ ba, float* __restrict__ out)
{
    const int tid = blockIdx.x * 256 + threadIdx.x;
    if (tid >= NGRAPHS * NACT) return;
    const int g = tid >> 5, a = tid & 31;
    float s = 0.f;
#pragma unroll
    for (int c = 0; c < HGAT_C; ++c)
        s += pooled[g * HGAT_C + c] * Wa[c * NACT + a];
    out[tid] = s + ba[a];
}

// ---------------------------------------------------------------------------
extern "C" void kernel_launch(void* const* d_in, const int* in_sizes, int n_in,
                              void* d_out, int out_size, void* d_ws, size_t ws_size,
                              hipStream_t stream)
{
    const float* x     = (const float*)d_in[0];
    const int*   ei    = (const int*)d_in[1];
    const int*   batch = (const int*)d_in[2];
    const float* W1    = (const float*)d_in[5];
    const float* as1   = (const float*)d_in[6];
    const float* ad1   = (const float*)d_in[7];
    const float* b1    = (const float*)d_in[8];
    const float* W2    = (const float*)d_in[9];
    const float* as2   = (const float*)d_in[10];
    const float* ad2   = (const float*)d_in[11];
    const float* b2    = (const float*)d_in[12];
    const float* Wa    = (const float*)d_in[13];
    const float* ba    = (const float*)d_in[14];

    const int N = in_sizes[0] / FIN;
    const int E = in_sizes[1] / 2;

    char* ws = (char*)d_ws;
    size_t off = 0;
    auto alloc = [&](size_t bytes) -> void* {
        void* p = ws + off;
        off += (bytes + 255) & ~(size_t)255;
        return p;
    };
    float* h1     = (float*)alloc((size_t)N * HGAT_HC * 4);  // projections
    float* hpost  = (float*)alloc((size_t)N * HGAT_HC * 4);  // L1 out / hfin
    float* a_src  = (float*)alloc((size_t)N * 4 * 4);
    float* a_dst  = (float*)alloc((size_t)N * 4 * 4);
    int*   rowptr = (int*)alloc((size_t)(N + 1) * 4);
    int*   colsrc = (int*)alloc((size_t)E * 4);
    int*   deg    = (int*)alloc((size_t)N * 4);
    int*   cursor = (int*)alloc((size_t)N * 4);
    float* pooled = (float*)alloc(NGRAPHS * HGAT_C * 4);
    float* hfin   = hpost;   // reuse: hpost dead after gemm2 reads it
    (void)ws_size; (void)n_in; (void)out_size;

    const dim3 gemmGrid((N + 127) / 128, HGAT_HC / 64);
    const int edgeBlocks     = (E + 255) / 256;
    const int nodeWaveBlocks = (N + 3) / 4;

    // ---------------- CSR build (shared by both layers) ----------------
    hipMemsetAsync(deg, 0, (size_t)N * 4, stream);
    count_deg_kernel<<<edgeBlocks, 256, 0, stream>>>(ei, deg, E);
    scan_kernel<<<1, 1024, 0, stream>>>(deg, rowptr, N);
    hipMemcpyAsync(cursor, rowptr, (size_t)N * 4, hipMemcpyDeviceToDevice, stream);
    fill_csr_kernel<<<edgeBlocks, 256, 0, stream>>>(ei, cursor, colsrc, E);

    // ---------------- layer 1 ----------------
    gemm_f32_kernel<<<gemmGrid, 256, 0, stream>>>(x, W1, h1, N, FIN, HGAT_HC);
    att_coef_kernel<<<nodeWaveBlocks, 256, 0, stream>>>(h1, as1, ad1, a_src, a_dst, N);
    aggregate_csr_kernel<0><<<nodeWaveBlocks, 256, 0, stream>>>(
        rowptr, colsrc, h1, a_src, a_dst, b1, hpost, N);

    // ---------------- layer 2 ----------------
    gemm_f32_kernel<<<gemmGrid, 256, 0, stream>>>(hpost, W2, h1, N, HGAT_HC, HGAT_HC);
    att_coef_kernel<<<nodeWaveBlocks, 256, 0, stream>>>(h1, as2, ad2, a_src, a_dst, N);
    aggregate_csr_kernel<1><<<nodeWaveBlocks, 256, 0, stream>>>(
        rowptr, colsrc, h1, a_src, a_dst, b2, hfin, N);

    // ---------------- pool + final ----------------
    pool_seg_kernel<<<NGRAPHS, 256, 0, stream>>>(hfin, batch, pooled, N);
    final_kernel<<<(NGRAPHS * NACT + 255) / 256, 256, 0, stream>>>(
        pooled, Wa, ba, (float*)d_out);
}

// Round 5
// 605.718 us; speedup vs baseline: 3.8624x; 1.1624x over previous
//
#include <hip/hip_runtime.h>
#include <hip/hip_bf16.h>
#include <cstdint>
#include <cstddef>

#define FIN      128
#define HGAT_H   4
#define HGAT_C   64
#define HGAT_HC  256
#define NGRAPHS  64
#define NACT     32

typedef unsigned int   uint32;
typedef unsigned short ushort_t;

__device__ __forceinline__ float bf2f(ushort_t u) {
    return __uint_as_float(((uint32)u) << 16);
}
__device__ __forceinline__ ushort_t f2bf(float f) {
    __hip_bfloat16 h = __float2bfloat16(f);   // RNE
    return *reinterpret_cast<ushort_t*>(&h);
}

// ---------------------------------------------------------------------------
// GEMM + attention epilogue.  C[M,256] = A[M,K] @ B[K,256]; block = 128 rows
// x 64 cols, and 64 cols == one head, so the epilogue computes the complete
// a_src/a_dst dots for its rows from the f32 accumulators (16-lane shfl
// reduce, no atomics) and writes C as bf16.
// A is f32 (layer 1: x) or bf16 (layer 2: hpost), staged to f32 in LDS.
// ---------------------------------------------------------------------------
template <bool ABF16>
__global__ __launch_bounds__(256) void gemm_att_kernel(
    const void* __restrict__ Av, const float* __restrict__ B,
    ushort_t* __restrict__ Cb, float* __restrict__ a_src,
    float* __restrict__ a_dst, const float* __restrict__ att_s,
    const float* __restrict__ att_d, int M, int K)
{
    __shared__ float As[32 * 132];   // As[kk*132 + m]
    __shared__ float Bs[32 * 68];    // Bs[kk*68 + n]

    const int t    = threadIdx.x;
    const int tx   = t & 15;
    const int ty   = t >> 4;
    const int m0   = blockIdx.x * 128;
    const int head = blockIdx.y;
    const int n0   = head * 64;

    float acc[8][4];
#pragma unroll
    for (int i = 0; i < 8; ++i)
#pragma unroll
        for (int j = 0; j < 4; ++j) acc[i][j] = 0.f;

    for (int k0 = 0; k0 < K; k0 += 32) {
        __syncthreads();
        {   // stage A (transposed)
            const int kk = (t & 7) * 4;
#pragma unroll
            for (int it = 0; it < 4; ++it) {
                int r  = (t >> 3) + it * 32;
                int gm = m0 + r; if (gm >= M) gm = M - 1;
                float4 v;
                if (ABF16) {
                    const ushort4 u = *reinterpret_cast<const ushort4*>(
                        (const ushort_t*)Av + (size_t)gm * K + k0 + kk);
                    v.x = bf2f(u.x); v.y = bf2f(u.y);
                    v.z = bf2f(u.z); v.w = bf2f(u.w);
                } else {
                    v = *reinterpret_cast<const float4*>(
                        (const float*)Av + (size_t)gm * K + k0 + kk);
                }
                As[(kk + 0) * 132 + r] = v.x;
                As[(kk + 1) * 132 + r] = v.y;
                As[(kk + 2) * 132 + r] = v.z;
                As[(kk + 3) * 132 + r] = v.w;
            }
        }
        {   // stage B
            const int col = tx * 4;
#pragma unroll
            for (int it = 0; it < 2; ++it) {
                const int kr = ty + it * 16;
                const float4 v = *reinterpret_cast<const float4*>(
                    &B[(size_t)(k0 + kr) * HGAT_HC + n0 + col]);
                *reinterpret_cast<float4*>(&Bs[kr * 68 + col]) = v;
            }
        }
        __syncthreads();

#pragma unroll
        for (int kk = 0; kk < 32; ++kk) {
            const float4 a0 = *reinterpret_cast<const float4*>(&As[kk * 132 + ty * 8]);
            const float4 a1 = *reinterpret_cast<const float4*>(&As[kk * 132 + ty * 8 + 4]);
            const float4 b  = *reinterpret_cast<const float4*>(&Bs[kk * 68 + tx * 4]);
            const float av[8] = {a0.x, a0.y, a0.z, a0.w, a1.x, a1.y, a1.z, a1.w};
#pragma unroll
            for (int i = 0; i < 8; ++i) {
                acc[i][0] += av[i] * b.x;
                acc[i][1] += av[i] * b.y;
                acc[i][2] += av[i] * b.z;
                acc[i][3] += av[i] * b.w;
            }
        }
    }

    // epilogue: bf16 C write + per-(row,head) attention dots
    const float4 ats = *reinterpret_cast<const float4*>(&att_s[n0 + tx * 4]);
    const float4 atd = *reinterpret_cast<const float4*>(&att_d[n0 + tx * 4]);
#pragma unroll
    for (int i = 0; i < 8; ++i) {
        const int gm = m0 + ty * 8 + i;
        float s = acc[i][0] * ats.x + acc[i][1] * ats.y
                + acc[i][2] * ats.z + acc[i][3] * ats.w;
        float d = acc[i][0] * atd.x + acc[i][1] * atd.y
                + acc[i][2] * atd.z + acc[i][3] * atd.w;
#pragma unroll
        for (int off = 1; off < 16; off <<= 1) {
            s += __shfl_xor(s, off);
            d += __shfl_xor(d, off);
        }
        if (gm < M) {
            ushort4 u;
            u.x = f2bf(acc[i][0]); u.y = f2bf(acc[i][1]);
            u.z = f2bf(acc[i][2]); u.w = f2bf(acc[i][3]);
            *reinterpret_cast<ushort4*>(&Cb[(size_t)gm * HGAT_HC + n0 + tx * 4]) = u;
            if (tx == 0) {
                a_src[gm * 4 + head] = s;
                a_dst[gm * 4 + head] = d;
            }
        }
    }
}

// ---------------------------------------------------------------------------
// CSR build: degree count, single-block scan, cursor fill.
// ---------------------------------------------------------------------------
__global__ __launch_bounds__(256) void count_deg_kernel(
    const int* __restrict__ ei, int* __restrict__ deg, int E)
{
    const int e = blockIdx.x * 256 + threadIdx.x;
    if (e < E) atomicAdd(&deg[ei[E + e]], 1);
}

__global__ __launch_bounds__(1024) void scan_kernel(
    const int* __restrict__ deg, int* __restrict__ rowptr, int N)
{
    __shared__ int sm[1024];
    const int tid = threadIdx.x;
    const int chunk = (N + 1023) >> 10;
    const int base = tid * chunk;
    int s = 0;
    for (int i = 0; i < chunk; ++i) {
        const int idx = base + i;
        if (idx < N) s += deg[idx];
    }
    sm[tid] = s;
    __syncthreads();
    for (int off = 1; off < 1024; off <<= 1) {
        int v = (tid >= off) ? sm[tid - off] : 0;
        __syncthreads();
        sm[tid] += v;
        __syncthreads();
    }
    int run = (tid == 0) ? 0 : sm[tid - 1];
    for (int i = 0; i < chunk; ++i) {
        const int idx = base + i;
        if (idx < N) { rowptr[idx] = run; run += deg[idx]; }
    }
    if (tid == 1023) rowptr[N] = sm[1023];
}

__global__ __launch_bounds__(256) void fill_csr_kernel(
    const int* __restrict__ ei, int* __restrict__ cursor,
    int* __restrict__ colsrc, int E)
{
    const int e = blockIdx.x * 256 + threadIdx.x;
    if (e >= E) return;
    const int d = ei[E + e];
    const int pos = atomicAdd(&cursor[d], 1);
    colsrc[pos] = ei[e];
}

// ---------------------------------------------------------------------------
// CSR aggregate (bf16 h gather, f32 accumulate), wave per dst node.
// MODE 0: concat + bias + ELU -> bf16 out[N,256].
// MODE 1: head-mean + bias + ELU -> bf16 out[N,64].
// ---------------------------------------------------------------------------
template <int MODE>
__global__ __launch_bounds__(256) void aggregate_csr_kernel(
    const int* __restrict__ rowptr, const int* __restrict__ colsrc,
    const ushort_t* __restrict__ hb, const float* __restrict__ a_src,
    const float* __restrict__ a_dst, const float* __restrict__ bias,
    ushort_t* __restrict__ out, int N)
{
    const int d    = (blockIdx.x * 256 + threadIdx.x) >> 6;
    const int lane = threadIdx.x & 63;
    if (d >= N) return;
    const int h  = lane >> 4;
    const int c0 = lane * 4;
    const float ad = a_dst[d * 4 + h];

    float4 acc = {0.f, 0.f, 0.f, 0.f};
    float  den = 0.f;

    const int beg = rowptr[d], end = rowptr[d + 1];
    for (int i = beg; i < end; ++i) {
        const int s = colsrc[i];
        float ee = a_src[s * 4 + h] + ad;
        ee = ee > 0.f ? ee : 0.2f * ee;
        const float w = expf(ee);
        const ushort4 u = *reinterpret_cast<const ushort4*>(
            &hb[(size_t)s * HGAT_HC + c0]);
        acc.x += w * bf2f(u.x); acc.y += w * bf2f(u.y);
        acc.z += w * bf2f(u.z); acc.w += w * bf2f(u.w);
        den += w;
    }
    {   // self loop
        float ee = a_src[d * 4 + h] + ad;
        ee = ee > 0.f ? ee : 0.2f * ee;
        const float w = expf(ee);
        const ushort4 u = *reinterpret_cast<const ushort4*>(
            &hb[(size_t)d * HGAT_HC + c0]);
        acc.x += w * bf2f(u.x); acc.y += w * bf2f(u.y);
        acc.z += w * bf2f(u.z); acc.w += w * bf2f(u.w);
        den += w;
    }

    const float inv = 1.0f / den;
    float4 v = {acc.x * inv, acc.y * inv, acc.z * inv, acc.w * inv};

    if (MODE == 0) {
        v.x += bias[c0 + 0]; v.y += bias[c0 + 1];
        v.z += bias[c0 + 2]; v.w += bias[c0 + 3];
        v.x = v.x > 0.f ? v.x : expm1f(v.x);
        v.y = v.y > 0.f ? v.y : expm1f(v.y);
        v.z = v.z > 0.f ? v.z : expm1f(v.z);
        v.w = v.w > 0.f ? v.w : expm1f(v.w);
        ushort4 u;
        u.x = f2bf(v.x); u.y = f2bf(v.y); u.z = f2bf(v.z); u.w = f2bf(v.w);
        *reinterpret_cast<ushort4*>(&out[(size_t)d * HGAT_HC + c0]) = u;
    } else {
        v.x += __shfl_xor(v.x, 16); v.x += __shfl_xor(v.x, 32);
        v.y += __shfl_xor(v.y, 16); v.y += __shfl_xor(v.y, 32);
        v.z += __shfl_xor(v.z, 16); v.z += __shfl_xor(v.z, 32);
        v.w += __shfl_xor(v.w, 16); v.w += __shfl_xor(v.w, 32);
        if (lane < 16) {
            const int c = lane * 4;
            float4 r;
            r.x = 0.25f * v.x + bias[c + 0];
            r.y = 0.25f * v.y + bias[c + 1];
            r.z = 0.25f * v.z + bias[c + 2];
            r.w = 0.25f * v.w + bias[c + 3];
            r.x = r.x > 0.f ? r.x : expm1f(r.x);
            r.y = r.y > 0.f ? r.y : expm1f(r.y);
            r.z = r.z > 0.f ? r.z : expm1f(r.z);
            r.w = r.w > 0.f ? r.w : expm1f(r.w);
            ushort4 u;
            u.x = f2bf(r.x); u.y = f2bf(r.y); u.z = f2bf(r.z); u.w = f2bf(r.w);
            *reinterpret_cast<ushort4*>(&out[(size_t)d * HGAT_C + c]) = u;
        }
    }
}

// ---------------------------------------------------------------------------
// Segmented mean pool over sorted batch (bf16 in, f32 out). No atomics.
// ---------------------------------------------------------------------------
__global__ __launch_bounds__(256) void pool_seg_kernel(
    const ushort_t* __restrict__ hfin, const int* __restrict__ batch,
    float* __restrict__ pooled, int N)
{
    const int g   = blockIdx.x;
    const int t   = threadIdx.x;
    const int c   = t & 63;
    const int sub = t >> 6;

    auto lower = [&](int key) {
        int lo = 0, hi = N;
        while (lo < hi) {
            const int mid = (lo + hi) >> 1;
            if (batch[mid] < key) lo = mid + 1; else hi = mid;
        }
        return lo;
    };
    const int beg = lower(g), end = lower(g + 1);

    float s = 0.f;
    for (int n = beg + sub; n < end; n += 4)
        s += bf2f(hfin[(size_t)n * HGAT_C + c]);

    __shared__ float sm[256];
    sm[t] = s;
    __syncthreads();
    if (sub == 0) {
        const float tot = sm[c] + sm[64 + c] + sm[128 + c] + sm[192 + c];
        const float inv = 1.0f / fmaxf((float)(end - beg), 1.0f);
        pooled[g * HGAT_C + c] = tot * inv;
    }
}

// ---------------------------------------------------------------------------
// Final: out[g,a] = pooled[g,:] @ Wa + ba
// ---------------------------------------------------------------------------
__global__ __launch_bounds__(256) void final_kernel(
    const float* __restrict__ pooled, const float* __restrict__ Wa,
    const float* __restrict__ ba, float* __restrict__ out)
{
    const int tid = blockIdx.x * 256 + threadIdx.x;
    if (tid >= NGRAPHS * NACT) return;
    const int g = tid >> 5, a = tid & 31;
    float s = 0.f;
#pragma unroll
    for (int c = 0; c < HGAT_C; ++c)
        s += pooled[g * HGAT_C + c] * Wa[c * NACT + a];
    out[tid] = s + ba[a];
}

// ---------------------------------------------------------------------------
extern "C" void kernel_launch(void* const* d_in, const int* in_sizes, int n_in,
                              void* d_out, int out_size, void* d_ws, size_t ws_size,
                              hipStream_t stream)
{
    const float* x     = (const float*)d_in[0];
    const int*   ei    = (const int*)d_in[1];
    const int*   batch = (const int*)d_in[2];
    const float* W1    = (const float*)d_in[5];
    const float* as1   = (const float*)d_in[6];
    const float* ad1   = (const float*)d_in[7];
    const float* b1    = (const float*)d_in[8];
    const float* W2    = (const float*)d_in[9];
    const float* as2   = (const float*)d_in[10];
    const float* ad2   = (const float*)d_in[11];
    const float* b2    = (const float*)d_in[12];
    const float* Wa    = (const float*)d_in[13];
    const float* ba    = (const float*)d_in[14];

    const int N = in_sizes[0] / FIN;
    const int E = in_sizes[1] / 2;

    char* ws = (char*)d_ws;
    size_t off = 0;
    auto alloc = [&](size_t bytes) -> void* {
        void* p = ws + off;
        off += (bytes + 255) & ~(size_t)255;
        return p;
    };
    ushort_t* hb     = (ushort_t*)alloc((size_t)N * HGAT_HC * 2);  // h (bf16), both layers
    ushort_t* hpost  = (ushort_t*)alloc((size_t)N * HGAT_HC * 2);  // L1 out (bf16) / hfin
    float*    a_src  = (float*)alloc((size_t)N * 4 * 4);
    float*    a_dst  = (float*)alloc((size_t)N * 4 * 4);
    int*      rowptr = (int*)alloc((size_t)(N + 1) * 4);
    int*      colsrc = (int*)alloc((size_t)E * 4);
    int*      deg    = (int*)alloc((size_t)N * 4);
    int*      cursor = (int*)alloc((size_t)N * 4);
    float*    pooled = (float*)alloc(NGRAPHS * HGAT_C * 4);
    ushort_t* hfin   = hpost;  // reuse: hpost consumed by gemm2 before agg<1> writes
    (void)ws_size; (void)n_in; (void)out_size;

    const dim3 gemmGrid((N + 127) / 128, HGAT_H);
    const int edgeBlocks     = (E + 255) / 256;
    const int nodeWaveBlocks = (N + 3) / 4;

    // ---------------- CSR build (shared by both layers) ----------------
    hipMemsetAsync(deg, 0, (size_t)N * 4, stream);
    count_deg_kernel<<<edgeBlocks, 256, 0, stream>>>(ei, deg, E);
    scan_kernel<<<1, 1024, 0, stream>>>(deg, rowptr, N);
    hipMemcpyAsync(cursor, rowptr, (size_t)N * 4, hipMemcpyDeviceToDevice, stream);
    fill_csr_kernel<<<edgeBlocks, 256, 0, stream>>>(ei, cursor, colsrc, E);

    // ---------------- layer 1 ----------------
    gemm_att_kernel<false><<<gemmGrid, 256, 0, stream>>>(
        x, W1, hb, a_src, a_dst, as1, ad1, N, FIN);
    aggregate_csr_kernel<0><<<nodeWaveBlocks, 256, 0, stream>>>(
        rowptr, colsrc, hb, a_src, a_dst, b1, hpost, N);

    // ---------------- layer 2 ----------------
    gemm_att_kernel<true><<<gemmGrid, 256, 0, stream>>>(
        hpost, W2, hb, a_src, a_dst, as2, ad2, N, HGAT_HC);
    aggregate_csr_kernel<1><<<nodeWaveBlocks, 256, 0, stream>>>(
        rowptr, colsrc, hb, a_src, a_dst, b2, hfin, N);

    // ---------------- pool + final ----------------
    pool_seg_kernel<<<NGRAPHS, 256, 0, stream>>>(hfin, batch, pooled, N);
    final_kernel<<<(NGRAPHS * NACT + 255) / 256, 256, 0, stream>>>(
        pooled, Wa, ba, (float*)d_out);
}

// Round 6
// 521.862 us; speedup vs baseline: 4.4830x; 1.1607x over previous
//
#include <hip/hip_runtime.h>
#include <hip/hip_bf16.h>
#include <cstdint>
#include <cstddef>

#define FIN      128
#define HGAT_H   4
#define HGAT_C   64
#define HGAT_HC  256
#define NGRAPHS  64
#define NACT     32

typedef unsigned int   uint32;
typedef unsigned short ushort_t;

using short8 = __attribute__((ext_vector_type(8))) short;
using f32x4  = __attribute__((ext_vector_type(4))) float;

__device__ __forceinline__ float bf2f(ushort_t u) {
    return __uint_as_float(((uint32)u) << 16);
}
__device__ __forceinline__ ushort_t f2bf(float f) {
    __hip_bfloat16 h = __float2bfloat16(f);   // RNE
    return *reinterpret_cast<ushort_t*>(&h);
}

// ---------------------------------------------------------------------------
// f32 -> bf16 cast, float4/thread.
// ---------------------------------------------------------------------------
__global__ __launch_bounds__(256) void f32_to_bf16_kernel(
    const float* __restrict__ in, ushort_t* __restrict__ out, int n4)
{
    const int i = blockIdx.x * 256 + threadIdx.x;
    if (i >= n4) return;
    const float4 v = reinterpret_cast<const float4*>(in)[i];
    ushort4 u;
    u.x = f2bf(v.x); u.y = f2bf(v.y); u.z = f2bf(v.z); u.w = f2bf(v.w);
    reinterpret_cast<ushort4*>(out)[i] = u;
}

// ---------------------------------------------------------------------------
// MFMA GEMM + attention epilogue.
// C[M,256] = A[M,K](bf16) @ B[K,256](f32, cast to bf16). Block: 128 rows x
// 64 cols (one head), 4 waves; wave w owns rows [w*32, w*32+32).
// B panel staged once to LDS transposed: Bt[col][k], stride K+8
// (16B-aligned rows; stride = 4 dwords mod 32 -> b128 lane reads tile the
// banks). A fragments read directly from global (no K-loop barrier).
// Epilogue: f32-acc attention dots (16-lane shfl reduce) + bf16 C store.
// mfma_f32_16x16x32_bf16: A row = lane&15, B col = lane&15,
// k = (lane>>4)*8 + j (A/B consistent); D: col=lane&15, row=(lane>>4)*4+reg.
// ---------------------------------------------------------------------------
template <int K>
__global__ __launch_bounds__(256) void gemm_mfma_att_kernel(
    const ushort_t* __restrict__ A, const float* __restrict__ B,
    ushort_t* __restrict__ Cb, float* __restrict__ a_src,
    float* __restrict__ a_dst, const float* __restrict__ att_s,
    const float* __restrict__ att_d, int M)
{
    constexpr int BSTR = K + 8;
    __shared__ ushort_t Bt[64 * BSTR];

    const int t    = threadIdx.x;
    const int m0   = blockIdx.x * 128;
    const int head = blockIdx.y;
    const int n0   = head * 64;

    {   // stage B panel (transposed, bf16)
        const int c = t & 63;
        for (int k = t >> 6; k < K; k += 4)
            Bt[c * BSTR + k] = f2bf(B[(size_t)k * HGAT_HC + n0 + c]);
    }
    __syncthreads();

    const int w  = t >> 6;
    const int l  = t & 63;
    const int lg = l >> 4;
    const int lr = l & 15;
    const int rowbase = m0 + w * 32;

    f32x4 acc[2][4];
#pragma unroll
    for (int i = 0; i < 2; ++i)
#pragma unroll
        for (int j = 0; j < 4; ++j) acc[i][j] = {0.f, 0.f, 0.f, 0.f};

    int gr[2];
#pragma unroll
    for (int rt = 0; rt < 2; ++rt) {
        const int gm = rowbase + rt * 16 + lr;
        gr[rt] = gm < M ? gm : M - 1;
    }

#pragma unroll
    for (int k0 = 0; k0 < K; k0 += 32) {
        short8 af[2], bfr[4];
#pragma unroll
        for (int rt = 0; rt < 2; ++rt)
            af[rt] = *reinterpret_cast<const short8*>(
                &A[(size_t)gr[rt] * K + k0 + lg * 8]);
#pragma unroll
        for (int ct = 0; ct < 4; ++ct)
            bfr[ct] = *reinterpret_cast<const short8*>(
                &Bt[(ct * 16 + lr) * BSTR + k0 + lg * 8]);
#pragma unroll
        for (int rt = 0; rt < 2; ++rt)
#pragma unroll
            for (int ct = 0; ct < 4; ++ct)
                acc[rt][ct] = __builtin_amdgcn_mfma_f32_16x16x32_bf16(
                    af[rt], bfr[ct], acc[rt][ct], 0, 0, 0);
    }

    // epilogue: attention dots + bf16 C
    float atsv[4], atdv[4];
#pragma unroll
    for (int ct = 0; ct < 4; ++ct) {
        atsv[ct] = att_s[n0 + ct * 16 + lr];
        atdv[ct] = att_d[n0 + ct * 16 + lr];
    }
#pragma unroll
    for (int rt = 0; rt < 2; ++rt) {
#pragma unroll
        for (int reg = 0; reg < 4; ++reg) {
            const int gm = rowbase + rt * 16 + lg * 4 + reg;
            float s = 0.f, d = 0.f;
#pragma unroll
            for (int ct = 0; ct < 4; ++ct) {
                const float v = acc[rt][ct][reg];
                s += v * atsv[ct];
                d += v * atdv[ct];
            }
#pragma unroll
            for (int off = 1; off < 16; off <<= 1) {
                s += __shfl_xor(s, off);
                d += __shfl_xor(d, off);
            }
            if (gm < M) {
#pragma unroll
                for (int ct = 0; ct < 4; ++ct)
                    Cb[(size_t)gm * HGAT_HC + n0 + ct * 16 + lr] =
                        f2bf(acc[rt][ct][reg]);
                if (lr == 0) {
                    a_src[gm * 4 + head] = s;
                    a_dst[gm * 4 + head] = d;
                }
            }
        }
    }
}

// ---------------------------------------------------------------------------
// CSR build: degree count, single-block scan, cursor fill.
// ---------------------------------------------------------------------------
__global__ __launch_bounds__(256) void count_deg_kernel(
    const int* __restrict__ ei, int* __restrict__ deg, int E)
{
    const int e = blockIdx.x * 256 + threadIdx.x;
    if (e < E) atomicAdd(&deg[ei[E + e]], 1);
}

__global__ __launch_bounds__(1024) void scan_kernel(
    const int* __restrict__ deg, int* __restrict__ rowptr, int N)
{
    __shared__ int sm[1024];
    const int tid = threadIdx.x;
    const int chunk = (N + 1023) >> 10;
    const int base = tid * chunk;
    int s = 0;
    for (int i = 0; i < chunk; ++i) {
        const int idx = base + i;
        if (idx < N) s += deg[idx];
    }
    sm[tid] = s;
    __syncthreads();
    for (int off = 1; off < 1024; off <<= 1) {
        int v = (tid >= off) ? sm[tid - off] : 0;
        __syncthreads();
        sm[tid] += v;
        __syncthreads();
    }
    int run = (tid == 0) ? 0 : sm[tid - 1];
    for (int i = 0; i < chunk; ++i) {
        const int idx = base + i;
        if (idx < N) { rowptr[idx] = run; run += deg[idx]; }
    }
    if (tid == 1023) rowptr[N] = sm[1023];
}

__global__ __launch_bounds__(256) void fill_csr_kernel(
    const int* __restrict__ ei, int* __restrict__ cursor,
    int* __restrict__ colsrc, int E)
{
    const int e = blockIdx.x * 256 + threadIdx.x;
    if (e >= E) return;
    const int d = ei[E + e];
    const int pos = atomicAdd(&cursor[d], 1);
    colsrc[pos] = ei[e];
}

// ---------------------------------------------------------------------------
// CSR aggregate (bf16 h gather, f32 accumulate), wave per dst node.
// MODE 0: concat + bias + ELU -> bf16 out[N,256].
// MODE 1: head-mean + bias + ELU -> bf16 out[N,64].
// ---------------------------------------------------------------------------
template <int MODE>
__global__ __launch_bounds__(256) void aggregate_csr_kernel(
    const int* __restrict__ rowptr, const int* __restrict__ colsrc,
    const ushort_t* __restrict__ hb, const float* __restrict__ a_src,
    const float* __restrict__ a_dst, const float* __restrict__ bias,
    ushort_t* __restrict__ out, int N)
{
    const int d    = (blockIdx.x * 256 + threadIdx.x) >> 6;
    const int lane = threadIdx.x & 63;
    if (d >= N) return;
    const int h  = lane >> 4;
    const int c0 = lane * 4;
    const float ad = a_dst[d * 4 + h];

    float4 acc = {0.f, 0.f, 0.f, 0.f};
    float  den = 0.f;

    const int beg = rowptr[d], end = rowptr[d + 1];
    for (int i = beg; i < end; ++i) {
        const int s = colsrc[i];
        float ee = a_src[s * 4 + h] + ad;
        ee = ee > 0.f ? ee : 0.2f * ee;
        const float w = expf(ee);
        const ushort4 u = *reinterpret_cast<const ushort4*>(
            &hb[(size_t)s * HGAT_HC + c0]);
        acc.x += w * bf2f(u.x); acc.y += w * bf2f(u.y);
        acc.z += w * bf2f(u.z); acc.w += w * bf2f(u.w);
        den += w;
    }
    {   // self loop
        float ee = a_src[d * 4 + h] + ad;
        ee = ee > 0.f ? ee : 0.2f * ee;
        const float w = expf(ee);
        const ushort4 u = *reinterpret_cast<const ushort4*>(
            &hb[(size_t)d * HGAT_HC + c0]);
        acc.x += w * bf2f(u.x); acc.y += w * bf2f(u.y);
        acc.z += w * bf2f(u.z); acc.w += w * bf2f(u.w);
        den += w;
    }

    const float inv = 1.0f / den;
    float4 v = {acc.x * inv, acc.y * inv, acc.z * inv, acc.w * inv};

    if (MODE == 0) {
        v.x += bias[c0 + 0]; v.y += bias[c0 + 1];
        v.z += bias[c0 + 2]; v.w += bias[c0 + 3];
        v.x = v.x > 0.f ? v.x : expm1f(v.x);
        v.y = v.y > 0.f ? v.y : expm1f(v.y);
        v.z = v.z > 0.f ? v.z : expm1f(v.z);
        v.w = v.w > 0.f ? v.w : expm1f(v.w);
        ushort4 u;
        u.x = f2bf(v.x); u.y = f2bf(v.y); u.z = f2bf(v.z); u.w = f2bf(v.w);
        *reinterpret_cast<ushort4*>(&out[(size_t)d * HGAT_HC + c0]) = u;
    } else {
        v.x += __shfl_xor(v.x, 16); v.x += __shfl_xor(v.x, 32);
        v.y += __shfl_xor(v.y, 16); v.y += __shfl_xor(v.y, 32);
        v.z += __shfl_xor(v.z, 16); v.z += __shfl_xor(v.z, 32);
        v.w += __shfl_xor(v.w, 16); v.w += __shfl_xor(v.w, 32);
        if (lane < 16) {
            const int c = lane * 4;
            float4 r;
            r.x = 0.25f * v.x + bias[c + 0];
            r.y = 0.25f * v.y + bias[c + 1];
            r.z = 0.25f * v.z + bias[c + 2];
            r.w = 0.25f * v.w + bias[c + 3];
            r.x = r.x > 0.f ? r.x : expm1f(r.x);
            r.y = r.y > 0.f ? r.y : expm1f(r.y);
            r.z = r.z > 0.f ? r.z : expm1f(r.z);
            r.w = r.w > 0.f ? r.w : expm1f(r.w);
            ushort4 u;
            u.x = f2bf(r.x); u.y = f2bf(r.y); u.z = f2bf(r.z); u.w = f2bf(r.w);
            *reinterpret_cast<ushort4*>(&out[(size_t)d * HGAT_C + c]) = u;
        }
    }
}

// ---------------------------------------------------------------------------
// Segmented mean pool over sorted batch (bf16 in, f32 out). No atomics.
// ---------------------------------------------------------------------------
__global__ __launch_bounds__(256) void pool_seg_kernel(
    const ushort_t* __restrict__ hfin, const int* __restrict__ batch,
    float* __restrict__ pooled, int N)
{
    const int g   = blockIdx.x;
    const int t   = threadIdx.x;
    const int c   = t & 63;
    const int sub = t >> 6;

    auto lower = [&](int key) {
        int lo = 0, hi = N;
        while (lo < hi) {
            const int mid = (lo + hi) >> 1;
            if (batch[mid] < key) lo = mid + 1; else hi = mid;
        }
        return lo;
    };
    const int beg = lower(g), end = lower(g + 1);

    float s = 0.f;
    for (int n = beg + sub; n < end; n += 4)
        s += bf2f(hfin[(size_t)n * HGAT_C + c]);

    __shared__ float sm[256];
    sm[t] = s;
    __syncthreads();
    if (sub == 0) {
        const float tot = sm[c] + sm[64 + c] + sm[128 + c] + sm[192 + c];
        const float inv = 1.0f / fmaxf((float)(end - beg), 1.0f);
        pooled[g * HGAT_C + c] = tot * inv;
    }
}

// ---------------------------------------------------------------------------
// Final: out[g,a] = pooled[g,:] @ Wa + ba
// ---------------------------------------------------------------------------
__global__ __launch_bounds__(256) void final_kernel(
    const float* __restrict__ pooled, const float* __restrict__ Wa,
    const float* __restrict__ ba, float* __restrict__ out)
{
    const int tid = blockIdx.x * 256 + threadIdx.x;
    if (tid >= NGRAPHS * NACT) return;
    const int g = tid >> 5, a = tid & 31;
    float s = 0.f;
#pragma unroll
    for (int c = 0; c < HGAT_C; ++c)
        s += pooled[g * HGAT_C + c] * Wa[c * NACT + a];
    out[tid] = s + ba[a];
}

// ---------------------------------------------------------------------------
extern "C" void kernel_launch(void* const* d_in, const int* in_sizes, int n_in,
                              void* d_out, int out_size, void* d_ws, size_t ws_size,
                              hipStream_t stream)
{
    const float* x     = (const float*)d_in[0];
    const int*   ei    = (const int*)d_in[1];
    const int*   batch = (const int*)d_in[2];
    const float* W1    = (const float*)d_in[5];
    const float* as1   = (const float*)d_in[6];
    const float* ad1   = (const float*)d_in[7];
    const float* b1    = (const float*)d_in[8];
    const float* W2    = (const float*)d_in[9];
    const float* as2   = (const float*)d_in[10];
    const float* ad2   = (const float*)d_in[11];
    const float* b2    = (const float*)d_in[12];
    const float* Wa    = (const float*)d_in[13];
    const float* ba    = (const float*)d_in[14];

    const int N = in_sizes[0] / FIN;
    const int E = in_sizes[1] / 2;

    char* ws = (char*)d_ws;
    size_t off = 0;
    auto alloc = [&](size_t bytes) -> void* {
        void* p = ws + off;
        off += (bytes + 255) & ~(size_t)255;
        return p;
    };
    ushort_t* hb     = (ushort_t*)alloc((size_t)N * HGAT_HC * 2);  // h (bf16)
    ushort_t* hpost  = (ushort_t*)alloc((size_t)N * HGAT_HC * 2);  // L1 out / hfin
    ushort_t* xb     = (ushort_t*)alloc((size_t)N * FIN * 2);      // x bf16
    float*    a_src  = (float*)alloc((size_t)N * 4 * 4);
    float*    a_dst  = (float*)alloc((size_t)N * 4 * 4);
    int*      rowptr = (int*)alloc((size_t)(N + 1) * 4);
    int*      colsrc = (int*)alloc((size_t)E * 4);
    int*      deg    = (int*)alloc((size_t)N * 4);
    int*      cursor = (int*)alloc((size_t)N * 4);
    float*    pooled = (float*)alloc(NGRAPHS * HGAT_C * 4);
    ushort_t* hfin   = hpost;  // reuse: hpost consumed by gemm2 before agg<1> writes
    (void)ws_size; (void)n_in; (void)out_size;

    const dim3 gemmGrid((N + 127) / 128, HGAT_H);
    const int edgeBlocks     = (E + 255) / 256;
    const int nodeWaveBlocks = (N + 3) / 4;

    // ---------------- CSR build (shared by both layers) ----------------
    hipMemsetAsync(deg, 0, (size_t)N * 4, stream);
    count_deg_kernel<<<edgeBlocks, 256, 0, stream>>>(ei, deg, E);
    scan_kernel<<<1, 1024, 0, stream>>>(deg, rowptr, N);
    hipMemcpyAsync(cursor, rowptr, (size_t)N * 4, hipMemcpyDeviceToDevice, stream);
    fill_csr_kernel<<<edgeBlocks, 256, 0, stream>>>(ei, cursor, colsrc, E);

    // ---------------- x -> bf16 ----------------
    f32_to_bf16_kernel<<<(N * FIN / 4 + 255) / 256, 256, 0, stream>>>(
        x, xb, N * FIN / 4);

    // ---------------- layer 1 ----------------
    gemm_mfma_att_kernel<FIN><<<gemmGrid, 256, 0, stream>>>(
        xb, W1, hb, a_src, a_dst, as1, ad1, N);
    aggregate_csr_kernel<0><<<nodeWaveBlocks, 256, 0, stream>>>(
        rowptr, colsrc, hb, a_src, a_dst, b1, hpost, N);

    // ---------------- layer 2 ----------------
    gemm_mfma_att_kernel<HGAT_HC><<<gemmGrid, 256, 0, stream>>>(
        hpost, W2, hb, a_src, a_dst, as2, ad2, N);
    aggregate_csr_kernel<1><<<nodeWaveBlocks, 256, 0, stream>>>(
        rowptr, colsrc, hb, a_src, a_dst, b2, hfin, N);

    // ---------------- pool + final ----------------
    pool_seg_kernel<<<NGRAPHS, 256, 0, stream>>>(hfin, batch, pooled, N);
    final_kernel<<<(NGRAPHS * NACT + 255) / 256, 256, 0, stream>>>(
        pooled, Wa, ba, (float*)d_out);
}

// Round 7
// 477.884 us; speedup vs baseline: 4.8956x; 1.0920x over previous
//
#include <hip/hip_runtime.h>
#include <hip/hip_bf16.h>
#include <cstdint>
#include <cstddef>

#define FIN      128
#define HGAT_H   4
#define HGAT_C   64
#define HGAT_HC  256
#define NGRAPHS  64
#define NACT     32

typedef unsigned int   uint32;
typedef unsigned short ushort_t;

using short8 = __attribute__((ext_vector_type(8))) short;
using f32x4  = __attribute__((ext_vector_type(4))) float;

__device__ __forceinline__ float bf2f(ushort_t u) {
    return __uint_as_float(((uint32)u) << 16);
}
__device__ __forceinline__ ushort_t f2bf(float f) {
    __hip_bfloat16 h = __float2bfloat16(f);   // RNE
    return *reinterpret_cast<ushort_t*>(&h);
}

// ---------------------------------------------------------------------------
// f32 -> bf16 cast, float4/thread.
// ---------------------------------------------------------------------------
__global__ __launch_bounds__(256) void f32_to_bf16_kernel(
    const float* __restrict__ in, ushort_t* __restrict__ out, int n4)
{
    const int i = blockIdx.x * 256 + threadIdx.x;
    if (i >= n4) return;
    const float4 v = reinterpret_cast<const float4*>(in)[i];
    ushort4 u;
    u.x = f2bf(v.x); u.y = f2bf(v.y); u.z = f2bf(v.z); u.w = f2bf(v.w);
    reinterpret_cast<ushort4*>(out)[i] = u;
}

// ---------------------------------------------------------------------------
// W[K][256] (f32) -> Wt[256][K] (bf16) transpose+cast.
// ---------------------------------------------------------------------------
__global__ __launch_bounds__(256) void wcast_kernel(
    const float* __restrict__ W, ushort_t* __restrict__ Wt, int K)
{
    const int idx = blockIdx.x * 256 + threadIdx.x;
    if (idx >= K * HGAT_HC) return;
    const int k = idx >> 8, c = idx & 255;
    Wt[(size_t)c * K + k] = f2bf(W[idx]);
}

// ---------------------------------------------------------------------------
// MFMA GEMM + attention epilogue. No LDS, no barriers.
// C[M,256] = A[M,K](bf16) @ Wt^T (Wt[256][K] bf16). Block = 64 rows, 4
// waves; wave w owns rows [w*16, w*16+16) and loops all 4 heads. A frags
// for the full K held in registers (A read ONCE from HBM); B frags read
// per head from L2-resident Wt (16B/lane contiguous).
// mfma_f32_16x16x32_bf16 maps: A row=lane&15, k=(lane>>4)*8+j; B col same;
// D: col=lane&15, row=(lane>>4)*4+reg (m89-verified).
// ---------------------------------------------------------------------------
template <int K>
__global__ __launch_bounds__(256) void gemm_mfma_att_kernel(
    const ushort_t* __restrict__ A, const ushort_t* __restrict__ Bt,
    ushort_t* __restrict__ Cb, float* __restrict__ a_src,
    float* __restrict__ a_dst, const float* __restrict__ att_s,
    const float* __restrict__ att_d, int M)
{
    const int t  = threadIdx.x;
    const int w  = t >> 6;
    const int l  = t & 63;
    const int lg = l >> 4;
    const int lr = l & 15;
    const int rowbase = blockIdx.x * 64 + w * 16;

    const int arow = rowbase + lr;
    const int gr   = arow < M ? arow : M - 1;

    short8 af[K / 32];
#pragma unroll
    for (int kk = 0; kk < K / 32; ++kk)
        af[kk] = *reinterpret_cast<const short8*>(
            &A[(size_t)gr * K + kk * 32 + lg * 8]);

#pragma unroll
    for (int head = 0; head < HGAT_H; ++head) {
        const ushort_t* Bh = Bt + (size_t)head * 64 * K;

        f32x4 acc[4];
#pragma unroll
        for (int ct = 0; ct < 4; ++ct) acc[ct] = {0.f, 0.f, 0.f, 0.f};

#pragma unroll
        for (int kk = 0; kk < K / 32; ++kk) {
            short8 bfr[4];
#pragma unroll
            for (int ct = 0; ct < 4; ++ct)
                bfr[ct] = *reinterpret_cast<const short8*>(
                    &Bh[(size_t)(ct * 16 + lr) * K + kk * 32 + lg * 8]);
#pragma unroll
            for (int ct = 0; ct < 4; ++ct)
                acc[ct] = __builtin_amdgcn_mfma_f32_16x16x32_bf16(
                    af[kk], bfr[ct], acc[ct], 0, 0, 0);
        }

        // epilogue: attention dots + bf16 C store for this head
        const int n0 = head * 64;
        float atsv[4], atdv[4];
#pragma unroll
        for (int ct = 0; ct < 4; ++ct) {
            atsv[ct] = att_s[n0 + ct * 16 + lr];
            atdv[ct] = att_d[n0 + ct * 16 + lr];
        }
#pragma unroll
        for (int reg = 0; reg < 4; ++reg) {
            const int gm = rowbase + lg * 4 + reg;
            float s = 0.f, d = 0.f;
#pragma unroll
            for (int ct = 0; ct < 4; ++ct) {
                const float v = acc[ct][reg];
                s += v * atsv[ct];
                d += v * atdv[ct];
            }
#pragma unroll
            for (int off = 1; off < 16; off <<= 1) {
                s += __shfl_xor(s, off);
                d += __shfl_xor(d, off);
            }
            if (gm < M) {
#pragma unroll
                for (int ct = 0; ct < 4; ++ct)
                    Cb[(size_t)gm * HGAT_HC + n0 + ct * 16 + lr] =
                        f2bf(acc[ct][reg]);
                if (lr == 0) {
                    a_src[gm * 4 + head] = s;
                    a_dst[gm * 4 + head] = d;
                }
            }
        }
    }
}

// ---------------------------------------------------------------------------
// CSR build: degree count, single-block scan, cursor fill.
// ---------------------------------------------------------------------------
__global__ __launch_bounds__(256) void count_deg_kernel(
    const int* __restrict__ ei, int* __restrict__ deg, int E)
{
    const int e = blockIdx.x * 256 + threadIdx.x;
    if (e < E) atomicAdd(&deg[ei[E + e]], 1);
}

__global__ __launch_bounds__(1024) void scan_kernel(
    const int* __restrict__ deg, int* __restrict__ rowptr, int N)
{
    __shared__ int sm[1024];
    const int tid = threadIdx.x;
    const int chunk = (N + 1023) >> 10;
    const int base = tid * chunk;
    int s = 0;
    for (int i = 0; i < chunk; ++i) {
        const int idx = base + i;
        if (idx < N) s += deg[idx];
    }
    sm[tid] = s;
    __syncthreads();
    for (int off = 1; off < 1024; off <<= 1) {
        int v = (tid >= off) ? sm[tid - off] : 0;
        __syncthreads();
        sm[tid] += v;
        __syncthreads();
    }
    int run = (tid == 0) ? 0 : sm[tid - 1];
    for (int i = 0; i < chunk; ++i) {
        const int idx = base + i;
        if (idx < N) { rowptr[idx] = run; run += deg[idx]; }
    }
    if (tid == 1023) rowptr[N] = sm[1023];
}

__global__ __launch_bounds__(256) void fill_csr_kernel(
    const int* __restrict__ ei, int* __restrict__ cursor,
    int* __restrict__ colsrc, int E)
{
    const int e = blockIdx.x * 256 + threadIdx.x;
    if (e >= E) return;
    const int d = ei[E + e];
    const int pos = atomicAdd(&cursor[d], 1);
    colsrc[pos] = ei[e];
}

// ---------------------------------------------------------------------------
// CSR aggregate (bf16 h gather, f32 accumulate), wave per dst node.
// 4-wide edge unroll: batch independent colsrc/a_src/h-row loads to break
// the serial gather-latency chain.
// MODE 0: concat + bias + ELU -> bf16 out[N,256].
// MODE 1: head-mean + bias + ELU -> bf16 out[N,64].
// ---------------------------------------------------------------------------
template <int MODE>
__global__ __launch_bounds__(256) void aggregate_csr_kernel(
    const int* __restrict__ rowptr, const int* __restrict__ colsrc,
    const ushort_t* __restrict__ hb, const float* __restrict__ a_src,
    const float* __restrict__ a_dst, const float* __restrict__ bias,
    ushort_t* __restrict__ out, int N)
{
    const int d    = (blockIdx.x * 256 + threadIdx.x) >> 6;
    const int lane = threadIdx.x & 63;
    if (d >= N) return;
    const int h  = lane >> 4;
    const int c0 = lane * 4;
    const float ad = a_dst[d * 4 + h];

    float4 acc = {0.f, 0.f, 0.f, 0.f};
    float  den = 0.f;

    const int beg = rowptr[d], end = rowptr[d + 1];
    int i = beg;
    for (; i + 4 <= end; i += 4) {
        const int s0 = colsrc[i + 0], s1 = colsrc[i + 1],
                  s2 = colsrc[i + 2], s3 = colsrc[i + 3];
        const float a0 = a_src[s0 * 4 + h], a1 = a_src[s1 * 4 + h],
                    a2 = a_src[s2 * 4 + h], a3 = a_src[s3 * 4 + h];
        const ushort4 u0 = *reinterpret_cast<const ushort4*>(&hb[(size_t)s0 * HGAT_HC + c0]);
        const ushort4 u1 = *reinterpret_cast<const ushort4*>(&hb[(size_t)s1 * HGAT_HC + c0]);
        const ushort4 u2 = *reinterpret_cast<const ushort4*>(&hb[(size_t)s2 * HGAT_HC + c0]);
        const ushort4 u3 = *reinterpret_cast<const ushort4*>(&hb[(size_t)s3 * HGAT_HC + c0]);

        float ee, wgt;
        ee = a0 + ad; ee = ee > 0.f ? ee : 0.2f * ee; wgt = expf(ee);
        acc.x += wgt * bf2f(u0.x); acc.y += wgt * bf2f(u0.y);
        acc.z += wgt * bf2f(u0.z); acc.w += wgt * bf2f(u0.w); den += wgt;
        ee = a1 + ad; ee = ee > 0.f ? ee : 0.2f * ee; wgt = expf(ee);
        acc.x += wgt * bf2f(u1.x); acc.y += wgt * bf2f(u1.y);
        acc.z += wgt * bf2f(u1.z); acc.w += wgt * bf2f(u1.w); den += wgt;
        ee = a2 + ad; ee = ee > 0.f ? ee : 0.2f * ee; wgt = expf(ee);
        acc.x += wgt * bf2f(u2.x); acc.y += wgt * bf2f(u2.y);
        acc.z += wgt * bf2f(u2.z); acc.w += wgt * bf2f(u2.w); den += wgt;
        ee = a3 + ad; ee = ee > 0.f ? ee : 0.2f * ee; wgt = expf(ee);
        acc.x += wgt * bf2f(u3.x); acc.y += wgt * bf2f(u3.y);
        acc.z += wgt * bf2f(u3.z); acc.w += wgt * bf2f(u3.w); den += wgt;
    }
    for (; i < end; ++i) {
        const int s = colsrc[i];
        float ee = a_src[s * 4 + h] + ad;
        ee = ee > 0.f ? ee : 0.2f * ee;
        const float wgt = expf(ee);
        const ushort4 u = *reinterpret_cast<const ushort4*>(&hb[(size_t)s * HGAT_HC + c0]);
        acc.x += wgt * bf2f(u.x); acc.y += wgt * bf2f(u.y);
        acc.z += wgt * bf2f(u.z); acc.w += wgt * bf2f(u.w);
        den += wgt;
    }
    {   // self loop
        float ee = a_src[d * 4 + h] + ad;
        ee = ee > 0.f ? ee : 0.2f * ee;
        const float wgt = expf(ee);
        const ushort4 u = *reinterpret_cast<const ushort4*>(&hb[(size_t)d * HGAT_HC + c0]);
        acc.x += wgt * bf2f(u.x); acc.y += wgt * bf2f(u.y);
        acc.z += wgt * bf2f(u.z); acc.w += wgt * bf2f(u.w);
        den += wgt;
    }

    const float inv = 1.0f / den;
    float4 v = {acc.x * inv, acc.y * inv, acc.z * inv, acc.w * inv};

    if (MODE == 0) {
        v.x += bias[c0 + 0]; v.y += bias[c0 + 1];
        v.z += bias[c0 + 2]; v.w += bias[c0 + 3];
        v.x = v.x > 0.f ? v.x : expm1f(v.x);
        v.y = v.y > 0.f ? v.y : expm1f(v.y);
        v.z = v.z > 0.f ? v.z : expm1f(v.z);
        v.w = v.w > 0.f ? v.w : expm1f(v.w);
        ushort4 u;
        u.x = f2bf(v.x); u.y = f2bf(v.y); u.z = f2bf(v.z); u.w = f2bf(v.w);
        *reinterpret_cast<ushort4*>(&out[(size_t)d * HGAT_HC + c0]) = u;
    } else {
        v.x += __shfl_xor(v.x, 16); v.x += __shfl_xor(v.x, 32);
        v.y += __shfl_xor(v.y, 16); v.y += __shfl_xor(v.y, 32);
        v.z += __shfl_xor(v.z, 16); v.z += __shfl_xor(v.z, 32);
        v.w += __shfl_xor(v.w, 16); v.w += __shfl_xor(v.w, 32);
        if (lane < 16) {
            const int c = lane * 4;
            float4 r;
            r.x = 0.25f * v.x + bias[c + 0];
            r.y = 0.25f * v.y + bias[c + 1];
            r.z = 0.25f * v.z + bias[c + 2];
            r.w = 0.25f * v.w + bias[c + 3];
            r.x = r.x > 0.f ? r.x : expm1f(r.x);
            r.y = r.y > 0.f ? r.y : expm1f(r.y);
            r.z = r.z > 0.f ? r.z : expm1f(r.z);
            r.w = r.w > 0.f ? r.w : expm1f(r.w);
            ushort4 u;
            u.x = f2bf(r.x); u.y = f2bf(r.y); u.z = f2bf(r.z); u.w = f2bf(r.w);
            *reinterpret_cast<ushort4*>(&out[(size_t)d * HGAT_C + c]) = u;
        }
    }
}

// ---------------------------------------------------------------------------
// Segmented mean pool over sorted batch (bf16 in, f32 out). No atomics.
// ---------------------------------------------------------------------------
__global__ __launch_bounds__(512) void pool_seg_kernel(
    const ushort_t* __restrict__ hfin, const int* __restrict__ batch,
    float* __restrict__ pooled, int N)
{
    const int g   = blockIdx.x;
    const int t   = threadIdx.x;
    const int c   = t & 63;
    const int sub = t >> 6;     // 0..7

    auto lower = [&](int key) {
        int lo = 0, hi = N;
        while (lo < hi) {
            const int mid = (lo + hi) >> 1;
            if (batch[mid] < key) lo = mid + 1; else hi = mid;
        }
        return lo;
    };
    const int beg = lower(g), end = lower(g + 1);

    float s = 0.f;
    for (int n = beg + sub; n < end; n += 8)
        s += bf2f(hfin[(size_t)n * HGAT_C + c]);

    __shared__ float sm[512];
    sm[t] = s;
    __syncthreads();
    if (sub == 0) {
        float tot = 0.f;
#pragma unroll
        for (int k = 0; k < 8; ++k) tot += sm[k * 64 + c];
        const float inv = 1.0f / fmaxf((float)(end - beg), 1.0f);
        pooled[g * HGAT_C + c] = tot * inv;
    }
}

// ---------------------------------------------------------------------------
// Final: out[g,a] = pooled[g,:] @ Wa + ba
// ---------------------------------------------------------------------------
__global__ __launch_bounds__(256) void final_kernel(
    const float* __restrict__ pooled, const float* __restrict__ Wa,
    const float* __restrict__ ba, float* __restrict__ out)
{
    const int tid = blockIdx.x * 256 + threadIdx.x;
    if (tid >= NGRAPHS * NACT) return;
    const int g = tid >> 5, a = tid & 31;
    float s = 0.f;
#pragma unroll
    for (int c = 0; c < HGAT_C; ++c)
        s += pooled[g * HGAT_C + c] * Wa[c * NACT + a];
    out[tid] = s + ba[a];
}

// ---------------------------------------------------------------------------
extern "C" void kernel_launch(void* const* d_in, const int* in_sizes, int n_in,
                              void* d_out, int out_size, void* d_ws, size_t ws_size,
                              hipStream_t stream)
{
    const float* x     = (const float*)d_in[0];
    const int*   ei    = (const int*)d_in[1];
    const int*   batch = (const int*)d_in[2];
    const float* W1    = (const float*)d_in[5];
    const float* as1   = (const float*)d_in[6];
    const float* ad1   = (const float*)d_in[7];
    const float* b1    = (const float*)d_in[8];
    const float* W2    = (const float*)d_in[9];
    const float* as2   = (const float*)d_in[10];
    const float* ad2   = (const float*)d_in[11];
    const float* b2    = (const float*)d_in[12];
    const float* Wa    = (const float*)d_in[13];
    const float* ba    = (const float*)d_in[14];

    const int N = in_sizes[0] / FIN;
    const int E = in_sizes[1] / 2;

    char* ws = (char*)d_ws;
    size_t off = 0;
    auto alloc = [&](size_t bytes) -> void* {
        void* p = ws + off;
        off += (bytes + 255) & ~(size_t)255;
        return p;
    };
    ushort_t* hb     = (ushort_t*)alloc((size_t)N * HGAT_HC * 2);  // h (bf16)
    ushort_t* hpost  = (ushort_t*)alloc((size_t)N * HGAT_HC * 2);  // L1 out / hfin
    ushort_t* xb     = (ushort_t*)alloc((size_t)N * FIN * 2);      // x bf16
    ushort_t* Wt1    = (ushort_t*)alloc((size_t)FIN * HGAT_HC * 2);
    ushort_t* Wt2    = (ushort_t*)alloc((size_t)HGAT_HC * HGAT_HC * 2);
    float*    a_src  = (float*)alloc((size_t)N * 4 * 4);
    float*    a_dst  = (float*)alloc((size_t)N * 4 * 4);
    int*      rowptr = (int*)alloc((size_t)(N + 1) * 4);
    int*      colsrc = (int*)alloc((size_t)E * 4);
    int*      deg    = (int*)alloc((size_t)N * 4);
    int*      cursor = (int*)alloc((size_t)N * 4);
    float*    pooled = (float*)alloc(NGRAPHS * HGAT_C * 4);
    ushort_t* hfin   = hpost;  // reuse: hpost consumed by gemm2 before agg<1> writes
    (void)ws_size; (void)n_in; (void)out_size;

    const int gemmBlocks     = (N + 63) / 64;
    const int edgeBlocks     = (E + 255) / 256;
    const int nodeWaveBlocks = (N + 3) / 4;

    // ---------------- CSR build (shared by both layers) ----------------
    hipMemsetAsync(deg, 0, (size_t)N * 4, stream);
    count_deg_kernel<<<edgeBlocks, 256, 0, stream>>>(ei, deg, E);
    scan_kernel<<<1, 1024, 0, stream>>>(deg, rowptr, N);
    hipMemcpyAsync(cursor, rowptr, (size_t)N * 4, hipMemcpyDeviceToDevice, stream);
    fill_csr_kernel<<<edgeBlocks, 256, 0, stream>>>(ei, cursor, colsrc, E);

    // ---------------- casts ----------------
    f32_to_bf16_kernel<<<(N * FIN / 4 + 255) / 256, 256, 0, stream>>>(
        x, xb, N * FIN / 4);
    wcast_kernel<<<(FIN * HGAT_HC + 255) / 256, 256, 0, stream>>>(W1, Wt1, FIN);
    wcast_kernel<<<(HGAT_HC * HGAT_HC + 255) / 256, 256, 0, stream>>>(W2, Wt2, HGAT_HC);

    // ---------------- layer 1 ----------------
    gemm_mfma_att_kernel<FIN><<<gemmBlocks, 256, 0, stream>>>(
        xb, Wt1, hb, a_src, a_dst, as1, ad1, N);
    aggregate_csr_kernel<0><<<nodeWaveBlocks, 256, 0, stream>>>(
        rowptr, colsrc, hb, a_src, a_dst, b1, hpost, N);

    // ---------------- layer 2 ----------------
    gemm_mfma_att_kernel<HGAT_HC><<<gemmBlocks, 256, 0, stream>>>(
        hpost, Wt2, hb, a_src, a_dst, as2, ad2, N);
    aggregate_csr_kernel<1><<<nodeWaveBlocks, 256, 0, stream>>>(
        rowptr, colsrc, hb, a_src, a_dst, b2, hfin, N);

    // ---------------- pool + final ----------------
    pool_seg_kernel<<<NGRAPHS, 512, 0, stream>>>(hfin, batch, pooled, N);
    final_kernel<<<(NGRAPHS * NACT + 255) / 256, 256, 0, stream>>>(
        pooled, Wa, ba, (float*)d_out);
}

// Round 8
// 397.120 us; speedup vs baseline: 5.8912x; 1.2034x over previous
//
#include <hip/hip_runtime.h>
#include <hip/hip_bf16.h>
#include <cstdint>
#include <cstddef>

#define FIN      128
#define HGAT_H   4
#define HGAT_C   64
#define HGAT_HC  256
#define NGRAPHS  64
#define NACT     32

typedef unsigned int   uint32;
typedef unsigned short ushort_t;

using short8 = __attribute__((ext_vector_type(8))) short;
using f32x4  = __attribute__((ext_vector_type(4))) float;

__device__ __forceinline__ float bf2f(ushort_t u) {
    return __uint_as_float(((uint32)u) << 16);
}
__device__ __forceinline__ ushort_t f2bf(float f) {
    __hip_bfloat16 h = __float2bfloat16(f);   // RNE
    return *reinterpret_cast<ushort_t*>(&h);
}

// ---------------------------------------------------------------------------
// f32 -> bf16 cast, float4/thread.
// ---------------------------------------------------------------------------
__global__ __launch_bounds__(256) void f32_to_bf16_kernel(
    const float* __restrict__ in, ushort_t* __restrict__ out, int n4)
{
    const int i = blockIdx.x * 256 + threadIdx.x;
    if (i >= n4) return;
    const float4 v = reinterpret_cast<const float4*>(in)[i];
    ushort4 u;
    u.x = f2bf(v.x); u.y = f2bf(v.y); u.z = f2bf(v.z); u.w = f2bf(v.w);
    reinterpret_cast<ushort4*>(out)[i] = u;
}

// ---------------------------------------------------------------------------
// W[K][256] (f32) -> Wt[256][K] (bf16) transpose+cast.
// ---------------------------------------------------------------------------
__global__ __launch_bounds__(256) void wcast_kernel(
    const float* __restrict__ W, ushort_t* __restrict__ Wt, int K)
{
    const int idx = blockIdx.x * 256 + threadIdx.x;
    if (idx >= K * HGAT_HC) return;
    const int k = idx >> 8, c = idx & 255;
    Wt[(size_t)c * K + k] = f2bf(W[idx]);
}

// ---------------------------------------------------------------------------
// MFMA GEMM + attention epilogue. No LDS, no barriers.
// C[M,256] = A[M,K](bf16) @ Wt^T (Wt[256][K] bf16). Block = 64 rows, 4
// waves; wave w owns rows [w*16, w*16+16) and loops all 4 heads. A frags
// for the full K held in registers (A read ONCE from HBM); B frags read
// per head from L2-resident Wt (16B/lane contiguous).
// ---------------------------------------------------------------------------
template <int K>
__global__ __launch_bounds__(256) void gemm_mfma_att_kernel(
    const ushort_t* __restrict__ A, const ushort_t* __restrict__ Bt,
    ushort_t* __restrict__ Cb, float* __restrict__ a_src,
    float* __restrict__ a_dst, const float* __restrict__ att_s,
    const float* __restrict__ att_d, int M)
{
    const int t  = threadIdx.x;
    const int w  = t >> 6;
    const int l  = t & 63;
    const int lg = l >> 4;
    const int lr = l & 15;
    const int rowbase = blockIdx.x * 64 + w * 16;

    const int arow = rowbase + lr;
    const int gr   = arow < M ? arow : M - 1;

    short8 af[K / 32];
#pragma unroll
    for (int kk = 0; kk < K / 32; ++kk)
        af[kk] = *reinterpret_cast<const short8*>(
            &A[(size_t)gr * K + kk * 32 + lg * 8]);

#pragma unroll
    for (int head = 0; head < HGAT_H; ++head) {
        const ushort_t* Bh = Bt + (size_t)head * 64 * K;

        f32x4 acc[4];
#pragma unroll
        for (int ct = 0; ct < 4; ++ct) acc[ct] = {0.f, 0.f, 0.f, 0.f};

#pragma unroll
        for (int kk = 0; kk < K / 32; ++kk) {
            short8 bfr[4];
#pragma unroll
            for (int ct = 0; ct < 4; ++ct)
                bfr[ct] = *reinterpret_cast<const short8*>(
                    &Bh[(size_t)(ct * 16 + lr) * K + kk * 32 + lg * 8]);
#pragma unroll
            for (int ct = 0; ct < 4; ++ct)
                acc[ct] = __builtin_amdgcn_mfma_f32_16x16x32_bf16(
                    af[kk], bfr[ct], acc[ct], 0, 0, 0);
        }

        // epilogue: attention dots + bf16 C store for this head
        const int n0 = head * 64;
        float atsv[4], atdv[4];
#pragma unroll
        for (int ct = 0; ct < 4; ++ct) {
            atsv[ct] = att_s[n0 + ct * 16 + lr];
            atdv[ct] = att_d[n0 + ct * 16 + lr];
        }
#pragma unroll
        for (int reg = 0; reg < 4; ++reg) {
            const int gm = rowbase + lg * 4 + reg;
            float s = 0.f, d = 0.f;
#pragma unroll
            for (int ct = 0; ct < 4; ++ct) {
                const float v = acc[ct][reg];
                s += v * atsv[ct];
                d += v * atdv[ct];
            }
#pragma unroll
            for (int off = 1; off < 16; off <<= 1) {
                s += __shfl_xor(s, off);
                d += __shfl_xor(d, off);
            }
            if (gm < M) {
#pragma unroll
                for (int ct = 0; ct < 4; ++ct)
                    Cb[(size_t)gm * HGAT_HC + n0 + ct * 16 + lr] =
                        f2bf(acc[ct][reg]);
                if (lr == 0) {
                    a_src[gm * 4 + head] = s;
                    a_dst[gm * 4 + head] = d;
                }
            }
        }
    }
}

// ---------------------------------------------------------------------------
// CSR build: degree count, hierarchical 3-launch scan, cursor fill.
// ---------------------------------------------------------------------------
__global__ __launch_bounds__(256) void count_deg_kernel(
    const int* __restrict__ ei, int* __restrict__ deg, int E)
{
    const int e = blockIdx.x * 256 + threadIdx.x;
    if (e < E) atomicAdd(&deg[ei[E + e]], 1);
}

// per-block sum of a 256-element chunk of deg
__global__ __launch_bounds__(256) void block_sum_kernel(
    const int* __restrict__ deg, int* __restrict__ bsum, int N)
{
    __shared__ int sm[256];
    const int idx = blockIdx.x * 256 + threadIdx.x;
    sm[threadIdx.x] = idx < N ? deg[idx] : 0;
    __syncthreads();
#pragma unroll
    for (int off = 128; off; off >>= 1) {
        if (threadIdx.x < off) sm[threadIdx.x] += sm[threadIdx.x + off];
        __syncthreads();
    }
    if (threadIdx.x == 0) bsum[blockIdx.x] = sm[0];
}

// single block: exclusive scan of NB (<=256) block sums, in place
__global__ __launch_bounds__(256) void scan_bsums_kernel(
    int* __restrict__ bsum, int NB)
{
    __shared__ int sm[256];
    const int t = threadIdx.x;
    int v = t < NB ? bsum[t] : 0;
    sm[t] = v;
    __syncthreads();
#pragma unroll
    for (int off = 1; off < 256; off <<= 1) {
        const int u = (t >= off) ? sm[t - off] : 0;
        __syncthreads();
        sm[t] += u;
        __syncthreads();
    }
    if (t < NB) bsum[t] = sm[t] - v;   // exclusive
}

// block-local scan + block offset -> rowptr
__global__ __launch_bounds__(256) void rowptr_kernel(
    const int* __restrict__ deg, const int* __restrict__ bsum,
    int* __restrict__ rowptr, int N)
{
    __shared__ int sm[256];
    const int t   = threadIdx.x;
    const int idx = blockIdx.x * 256 + t;
    const int v   = idx < N ? deg[idx] : 0;
    sm[t] = v;
    __syncthreads();
#pragma unroll
    for (int off = 1; off < 256; off <<= 1) {
        const int u = (t >= off) ? sm[t - off] : 0;
        __syncthreads();
        sm[t] += u;
        __syncthreads();
    }
    const int base = bsum[blockIdx.x];
    if (idx < N) rowptr[idx] = base + sm[t] - v;          // exclusive
    if (idx == N - 1) rowptr[N] = base + sm[t];           // total = E
}

__global__ __launch_bounds__(256) void fill_csr_kernel(
    const int* __restrict__ ei, int* __restrict__ cursor,
    int* __restrict__ colsrc, int E)
{
    const int e = blockIdx.x * 256 + threadIdx.x;
    if (e >= E) return;
    const int d = ei[E + e];
    const int pos = atomicAdd(&cursor[d], 1);
    colsrc[pos] = ei[e];
}

// ---------------------------------------------------------------------------
// CSR aggregate (bf16 h gather, f32 accumulate), wave per dst node.
// 4-wide edge unroll to break the serial gather-latency chain.
// MODE 0: concat + bias + ELU -> bf16 out[N,256].
// MODE 1: head-mean + bias + ELU -> bf16 out[N,64].
// ---------------------------------------------------------------------------
template <int MODE>
__global__ __launch_bounds__(256) void aggregate_csr_kernel(
    const int* __restrict__ rowptr, const int* __restrict__ colsrc,
    const ushort_t* __restrict__ hb, const float* __restrict__ a_src,
    const float* __restrict__ a_dst, const float* __restrict__ bias,
    ushort_t* __restrict__ out, int N)
{
    const int d    = (blockIdx.x * 256 + threadIdx.x) >> 6;
    const int lane = threadIdx.x & 63;
    if (d >= N) return;
    const int h  = lane >> 4;
    const int c0 = lane * 4;
    const float ad = a_dst[d * 4 + h];

    float4 acc = {0.f, 0.f, 0.f, 0.f};
    float  den = 0.f;

    const int beg = rowptr[d], end = rowptr[d + 1];
    int i = beg;
    for (; i + 4 <= end; i += 4) {
        const int s0 = colsrc[i + 0], s1 = colsrc[i + 1],
                  s2 = colsrc[i + 2], s3 = colsrc[i + 3];
        const float a0 = a_src[s0 * 4 + h], a1 = a_src[s1 * 4 + h],
                    a2 = a_src[s2 * 4 + h], a3 = a_src[s3 * 4 + h];
        const ushort4 u0 = *reinterpret_cast<const ushort4*>(&hb[(size_t)s0 * HGAT_HC + c0]);
        const ushort4 u1 = *reinterpret_cast<const ushort4*>(&hb[(size_t)s1 * HGAT_HC + c0]);
        const ushort4 u2 = *reinterpret_cast<const ushort4*>(&hb[(size_t)s2 * HGAT_HC + c0]);
        const ushort4 u3 = *reinterpret_cast<const ushort4*>(&hb[(size_t)s3 * HGAT_HC + c0]);

        float ee, wgt;
        ee = a0 + ad; ee = ee > 0.f ? ee : 0.2f * ee; wgt = expf(ee);
        acc.x += wgt * bf2f(u0.x); acc.y += wgt * bf2f(u0.y);
        acc.z += wgt * bf2f(u0.z); acc.w += wgt * bf2f(u0.w); den += wgt;
        ee = a1 + ad; ee = ee > 0.f ? ee : 0.2f * ee; wgt = expf(ee);
        acc.x += wgt * bf2f(u1.x); acc.y += wgt * bf2f(u1.y);
        acc.z += wgt * bf2f(u1.z); acc.w += wgt * bf2f(u1.w); den += wgt;
        ee = a2 + ad; ee = ee > 0.f ? ee : 0.2f * ee; wgt = expf(ee);
        acc.x += wgt * bf2f(u2.x); acc.y += wgt * bf2f(u2.y);
        acc.z += wgt * bf2f(u2.z); acc.w += wgt * bf2f(u2.w); den += wgt;
        ee = a3 + ad; ee = ee > 0.f ? ee : 0.2f * ee; wgt = expf(ee);
        acc.x += wgt * bf2f(u3.x); acc.y += wgt * bf2f(u3.y);
        acc.z += wgt * bf2f(u3.z); acc.w += wgt * bf2f(u3.w); den += wgt;
    }
    for (; i < end; ++i) {
        const int s = colsrc[i];
        float ee = a_src[s * 4 + h] + ad;
        ee = ee > 0.f ? ee : 0.2f * ee;
        const float wgt = expf(ee);
        const ushort4 u = *reinterpret_cast<const ushort4*>(&hb[(size_t)s * HGAT_HC + c0]);
        acc.x += wgt * bf2f(u.x); acc.y += wgt * bf2f(u.y);
        acc.z += wgt * bf2f(u.z); acc.w += wgt * bf2f(u.w);
        den += wgt;
    }
    {   // self loop
        float ee = a_src[d * 4 + h] + ad;
        ee = ee > 0.f ? ee : 0.2f * ee;
        const float wgt = expf(ee);
        const ushort4 u = *reinterpret_cast<const ushort4*>(&hb[(size_t)d * HGAT_HC + c0]);
        acc.x += wgt * bf2f(u.x); acc.y += wgt * bf2f(u.y);
        acc.z += wgt * bf2f(u.z); acc.w += wgt * bf2f(u.w);
        den += wgt;
    }

    const float inv = 1.0f / den;
    float4 v = {acc.x * inv, acc.y * inv, acc.z * inv, acc.w * inv};

    if (MODE == 0) {
        v.x += bias[c0 + 0]; v.y += bias[c0 + 1];
        v.z += bias[c0 + 2]; v.w += bias[c0 + 3];
        v.x = v.x > 0.f ? v.x : expm1f(v.x);
        v.y = v.y > 0.f ? v.y : expm1f(v.y);
        v.z = v.z > 0.f ? v.z : expm1f(v.z);
        v.w = v.w > 0.f ? v.w : expm1f(v.w);
        ushort4 u;
        u.x = f2bf(v.x); u.y = f2bf(v.y); u.z = f2bf(v.z); u.w = f2bf(v.w);
        *reinterpret_cast<ushort4*>(&out[(size_t)d * HGAT_HC + c0]) = u;
    } else {
        v.x += __shfl_xor(v.x, 16); v.x += __shfl_xor(v.x, 32);
        v.y += __shfl_xor(v.y, 16); v.y += __shfl_xor(v.y, 32);
        v.z += __shfl_xor(v.z, 16); v.z += __shfl_xor(v.z, 32);
        v.w += __shfl_xor(v.w, 16); v.w += __shfl_xor(v.w, 32);
        if (lane < 16) {
            const int c = lane * 4;
            float4 r;
            r.x = 0.25f * v.x + bias[c + 0];
            r.y = 0.25f * v.y + bias[c + 1];
            r.z = 0.25f * v.z + bias[c + 2];
            r.w = 0.25f * v.w + bias[c + 3];
            r.x = r.x > 0.f ? r.x : expm1f(r.x);
            r.y = r.y > 0.f ? r.y : expm1f(r.y);
            r.z = r.z > 0.f ? r.z : expm1f(r.z);
            r.w = r.w > 0.f ? r.w : expm1f(r.w);
            ushort4 u;
            u.x = f2bf(r.x); u.y = f2bf(r.y); u.z = f2bf(r.z); u.w = f2bf(r.w);
            *reinterpret_cast<ushort4*>(&out[(size_t)d * HGAT_C + c]) = u;
        }
    }
}

// ---------------------------------------------------------------------------
// Segmented mean pool over sorted batch (bf16 in, f32 out). No atomics.
// ---------------------------------------------------------------------------
__global__ __launch_bounds__(512) void pool_seg_kernel(
    const ushort_t* __restrict__ hfin, const int* __restrict__ batch,
    float* __restrict__ pooled, int N)
{
    const int g   = blockIdx.x;
    const int t   = threadIdx.x;
    const int c   = t & 63;
    const int sub = t >> 6;     // 0..7

    auto lower = [&](int key) {
        int lo = 0, hi = N;
        while (lo < hi) {
            const int mid = (lo + hi) >> 1;
            if (batch[mid] < key) lo = mid + 1; else hi = mid;
        }
        return lo;
    };
    const int beg = lower(g), end = lower(g + 1);

    float s = 0.f;
    for (int n = beg + sub; n < end; n += 8)
        s += bf2f(hfin[(size_t)n * HGAT_C + c]);

    __shared__ float sm[512];
    sm[t] = s;
    __syncthreads();
    if (sub == 0) {
        float tot = 0.f;
#pragma unroll
        for (int k = 0; k < 8; ++k) tot += sm[k * 64 + c];
        const float inv = 1.0f / fmaxf((float)(end - beg), 1.0f);
        pooled[g * HGAT_C + c] = tot * inv;
    }
}

// ---------------------------------------------------------------------------
// Final: out[g,a] = pooled[g,:] @ Wa + ba
// ---------------------------------------------------------------------------
__global__ __launch_bounds__(256) void final_kernel(
    const float* __restrict__ pooled, const float* __restrict__ Wa,
    const float* __restrict__ ba, float* __restrict__ out)
{
    const int tid = blockIdx.x * 256 + threadIdx.x;
    if (tid >= NGRAPHS * NACT) return;
    const int g = tid >> 5, a = tid & 31;
    float s = 0.f;
#pragma unroll
    for (int c = 0; c < HGAT_C; ++c)
        s += pooled[g * HGAT_C + c] * Wa[c * NACT + a];
    out[tid] = s + ba[a];
}

// ---------------------------------------------------------------------------
extern "C" void kernel_launch(void* const* d_in, const int* in_sizes, int n_in,
                              void* d_out, int out_size, void* d_ws, size_t ws_size,
                              hipStream_t stream)
{
    const float* x     = (const float*)d_in[0];
    const int*   ei    = (const int*)d_in[1];
    const int*   batch = (const int*)d_in[2];
    const float* W1    = (const float*)d_in[5];
    const float* as1   = (const float*)d_in[6];
    const float* ad1   = (const float*)d_in[7];
    const float* b1    = (const float*)d_in[8];
    const float* W2    = (const float*)d_in[9];
    const float* as2   = (const float*)d_in[10];
    const float* ad2   = (const float*)d_in[11];
    const float* b2    = (const float*)d_in[12];
    const float* Wa    = (const float*)d_in[13];
    const float* ba    = (const float*)d_in[14];

    const int N = in_sizes[0] / FIN;
    const int E = in_sizes[1] / 2;

    char* ws = (char*)d_ws;
    size_t off = 0;
    auto alloc = [&](size_t bytes) -> void* {
        void* p = ws + off;
        off += (bytes + 255) & ~(size_t)255;
        return p;
    };
    ushort_t* hb     = (ushort_t*)alloc((size_t)N * HGAT_HC * 2);  // h (bf16)
    ushort_t* hpost  = (ushort_t*)alloc((size_t)N * HGAT_HC * 2);  // L1 out / hfin
    ushort_t* xb     = (ushort_t*)alloc((size_t)N * FIN * 2);      // x bf16
    ushort_t* Wt1    = (ushort_t*)alloc((size_t)FIN * HGAT_HC * 2);
    ushort_t* Wt2    = (ushort_t*)alloc((size_t)HGAT_HC * HGAT_HC * 2);
    float*    a_src  = (float*)alloc((size_t)N * 4 * 4);
    float*    a_dst  = (float*)alloc((size_t)N * 4 * 4);
    int*      rowptr = (int*)alloc((size_t)(N + 1) * 4);
    int*      colsrc = (int*)alloc((size_t)E * 4);
    int*      deg    = (int*)alloc((size_t)N * 4);
    int*      cursor = (int*)alloc((size_t)N * 4);
    int*      bsum   = (int*)alloc(256 * 4);
    float*    pooled = (float*)alloc(NGRAPHS * HGAT_C * 4);
    ushort_t* hfin   = hpost;  // reuse: hpost consumed by gemm2 before agg<1> writes
    (void)ws_size; (void)n_in; (void)out_size;

    const int gemmBlocks     = (N + 63) / 64;
    const int edgeBlocks     = (E + 255) / 256;
    const int nodeWaveBlocks = (N + 3) / 4;
    const int NB             = (N + 255) / 256;   // <= 256 for N <= 65536

    // ---------------- CSR build (shared by both layers) ----------------
    hipMemsetAsync(deg, 0, (size_t)N * 4, stream);
    count_deg_kernel<<<edgeBlocks, 256, 0, stream>>>(ei, deg, E);
    block_sum_kernel<<<NB, 256, 0, stream>>>(deg, bsum, N);
    scan_bsums_kernel<<<1, 256, 0, stream>>>(bsum, NB);
    rowptr_kernel<<<NB, 256, 0, stream>>>(deg, bsum, rowptr, N);
    hipMemcpyAsync(cursor, rowptr, (size_t)N * 4, hipMemcpyDeviceToDevice, stream);
    fill_csr_kernel<<<edgeBlocks, 256, 0, stream>>>(ei, cursor, colsrc, E);

    // ---------------- casts ----------------
    f32_to_bf16_kernel<<<(N * FIN / 4 + 255) / 256, 256, 0, stream>>>(
        x, xb, N * FIN / 4);
    wcast_kernel<<<(FIN * HGAT_HC + 255) / 256, 256, 0, stream>>>(W1, Wt1, FIN);
    wcast_kernel<<<(HGAT_HC * HGAT_HC + 255) / 256, 256, 0, stream>>>(W2, Wt2, HGAT_HC);

    // ---------------- layer 1 ----------------
    gemm_mfma_att_kernel<FIN><<<gemmBlocks, 256, 0, stream>>>(
        xb, Wt1, hb, a_src, a_dst, as1, ad1, N);
    aggregate_csr_kernel<0><<<nodeWaveBlocks, 256, 0, stream>>>(
        rowptr, colsrc, hb, a_src, a_dst, b1, hpost, N);

    // ---------------- layer 2 ----------------
    gemm_mfma_att_kernel<HGAT_HC><<<gemmBlocks, 256, 0, stream>>>(
        hpost, Wt2, hb, a_src, a_dst, as2, ad2, N);
    aggregate_csr_kernel<1><<<nodeWaveBlocks, 256, 0, stream>>>(
        rowptr, colsrc, hb, a_src, a_dst, b2, hfin, N);

    // ---------------- pool + final ----------------
    pool_seg_kernel<<<NGRAPHS, 512, 0, stream>>>(hfin, batch, pooled, N);
    final_kernel<<<(NGRAPHS * NACT + 255) / 256, 256, 0, stream>>>(
        pooled, Wa, ba, (float*)d_out);
}

// Round 9
// 315.504 us; speedup vs baseline: 7.4152x; 1.2587x over previous
//
#include <hip/hip_runtime.h>
#include <hip/hip_bf16.h>
#include <cstdint>
#include <cstddef>

#define FIN      128
#define HGAT_H   4
#define HGAT_C   64
#define HGAT_HC  256
#define NGRAPHS  64
#define NACT     32
#define LOG2E    1.4426950408889634f

typedef unsigned int   uint32;
typedef unsigned short ushort_t;

using short8 = __attribute__((ext_vector_type(8))) short;
using u16x8  = __attribute__((ext_vector_type(8))) ushort_t;
using f32x4  = __attribute__((ext_vector_type(4))) float;

__device__ __forceinline__ float bf2f(ushort_t u) {
    return __uint_as_float(((uint32)u) << 16);
}
__device__ __forceinline__ float bflo(uint32 q) {   // low bf16 of packed pair
    return __uint_as_float(q << 16);
}
__device__ __forceinline__ float bfhi(uint32 q) {   // high bf16 of packed pair
    return __uint_as_float(q & 0xFFFF0000u);
}
__device__ __forceinline__ ushort_t f2bf(float f) {
    __hip_bfloat16 h = __float2bfloat16(f);   // RNE
    return *reinterpret_cast<ushort_t*>(&h);
}

// ---------------------------------------------------------------------------
// W[K][256] (f32) -> Wt[256][K] (bf16) transpose+cast.
// ---------------------------------------------------------------------------
__global__ __launch_bounds__(256) void wcast_kernel(
    const float* __restrict__ W, ushort_t* __restrict__ Wt, int K)
{
    const int idx = blockIdx.x * 256 + threadIdx.x;
    if (idx >= K * HGAT_HC) return;
    const int k = idx >> 8, c = idx & 255;
    Wt[(size_t)c * K + k] = f2bf(W[idx]);
}

// ---------------------------------------------------------------------------
// MFMA GEMM + attention epilogue.  C[M,256] = A[M,K] @ Wt^T.
// Block = 128 rows, 4 waves; wave w owns rows [w*32, w*32+32) as 2 row-tiles.
// Per head: stage Bh (64 x K bf16) into LDS (stride K+8 -> uniform bank
// spread), all 4 waves consume via ds_read_b128. A frags in registers for
// the whole kernel (A read once; AF32 converts f32 x on the fly).
// Epilogue: attention dots (pre-scaled by LOG2E for the exp2 consumer)
// via 16-lane shfl reduce + bf16 C store.
// mfma_f32_16x16x32_bf16 D map: col=lane&15, row=(lane>>4)*4+reg.
// ---------------------------------------------------------------------------
template <int K, bool AF32>
__global__ __launch_bounds__(256) void gemm_mfma_att_kernel(
    const void* __restrict__ Av, const ushort_t* __restrict__ Bt,
    ushort_t* __restrict__ Cb, float* __restrict__ a_src,
    float* __restrict__ a_dst, const float* __restrict__ att_s,
    const float* __restrict__ att_d, int M)
{
    constexpr int KK   = K / 32;
    constexpr int BSTR = K + 8;
    __shared__ ushort_t Bs[64 * BSTR];

    const int t  = threadIdx.x;
    const int w  = t >> 6;
    const int l  = t & 63;
    const int lg = l >> 4;
    const int lr = l & 15;
    const int rowbase = blockIdx.x * 128 + w * 32;

    // ---- A fragments: 2 row-tiles x KK k-steps, registers for whole kernel
    short8 af[2][KK];
#pragma unroll
    for (int rt = 0; rt < 2; ++rt) {
        const int arow = rowbase + rt * 16 + lr;
        const int gr   = arow < M ? arow : M - 1;
        if (AF32) {
            const float* Ap = (const float*)Av + (size_t)gr * K;
#pragma unroll
            for (int kk = 0; kk < KK; ++kk) {
                const float4 v0 = *reinterpret_cast<const float4*>(Ap + kk * 32 + lg * 8);
                const float4 v1 = *reinterpret_cast<const float4*>(Ap + kk * 32 + lg * 8 + 4);
                short8 s;
                s[0] = (short)f2bf(v0.x); s[1] = (short)f2bf(v0.y);
                s[2] = (short)f2bf(v0.z); s[3] = (short)f2bf(v0.w);
                s[4] = (short)f2bf(v1.x); s[5] = (short)f2bf(v1.y);
                s[6] = (short)f2bf(v1.z); s[7] = (short)f2bf(v1.w);
                af[rt][kk] = s;
            }
        } else {
            const ushort_t* Ap = (const ushort_t*)Av + (size_t)gr * K;
#pragma unroll
            for (int kk = 0; kk < KK; ++kk)
                af[rt][kk] = *reinterpret_cast<const short8*>(Ap + kk * 32 + lg * 8);
        }
    }

#pragma unroll
    for (int head = 0; head < HGAT_H; ++head) {
        __syncthreads();   // protect Bs from previous head's readers
        {   // stage head panel: row r = t&63, cols [(t>>6)*K/4, +K/4)
            const int r     = t & 63;
            const int cbase = (t >> 6) * (K / 4);
            const ushort_t* src = Bt + ((size_t)head * 64 + r) * K + cbase;
            ushort_t*       dst = &Bs[r * BSTR + cbase];
#pragma unroll
            for (int j = 0; j < K / 32; ++j)
                *reinterpret_cast<u16x8*>(dst + j * 8) =
                    *reinterpret_cast<const u16x8*>(src + j * 8);
        }
        __syncthreads();

        f32x4 acc[2][4];
#pragma unroll
        for (int rt = 0; rt < 2; ++rt)
#pragma unroll
            for (int ct = 0; ct < 4; ++ct) acc[rt][ct] = {0.f, 0.f, 0.f, 0.f};

#pragma unroll
        for (int kk = 0; kk < KK; ++kk) {
            short8 bfr[4];
#pragma unroll
            for (int ct = 0; ct < 4; ++ct)
                bfr[ct] = *reinterpret_cast<const short8*>(
                    &Bs[(ct * 16 + lr) * BSTR + kk * 32 + lg * 8]);
#pragma unroll
            for (int rt = 0; rt < 2; ++rt)
#pragma unroll
                for (int ct = 0; ct < 4; ++ct)
                    acc[rt][ct] = __builtin_amdgcn_mfma_f32_16x16x32_bf16(
                        af[rt][kk], bfr[ct], acc[rt][ct], 0, 0, 0);
        }

        // epilogue: attention dots + bf16 C store for this head
        const int n0 = head * 64;
        float atsv[4], atdv[4];
#pragma unroll
        for (int ct = 0; ct < 4; ++ct) {
            atsv[ct] = att_s[n0 + ct * 16 + lr];
            atdv[ct] = att_d[n0 + ct * 16 + lr];
        }
#pragma unroll
        for (int rt = 0; rt < 2; ++rt) {
#pragma unroll
            for (int reg = 0; reg < 4; ++reg) {
                const int gm = rowbase + rt * 16 + lg * 4 + reg;
                float s = 0.f, d = 0.f;
#pragma unroll
                for (int ct = 0; ct < 4; ++ct) {
                    const float v = acc[rt][ct][reg];
                    s += v * atsv[ct];
                    d += v * atdv[ct];
                }
#pragma unroll
                for (int off = 1; off < 16; off <<= 1) {
                    s += __shfl_xor(s, off);
                    d += __shfl_xor(d, off);
                }
                if (gm < M) {
#pragma unroll
                    for (int ct = 0; ct < 4; ++ct)
                        Cb[(size_t)gm * HGAT_HC + n0 + ct * 16 + lr] =
                            f2bf(acc[rt][ct][reg]);
                    if (lr == 0) {
                        a_src[gm * 4 + head] = s * LOG2E;  // pre-scaled for exp2
                        a_dst[gm * 4 + head] = d * LOG2E;
                    }
                }
            }
        }
    }
}

// ---------------------------------------------------------------------------
// CSR build: degree count, hierarchical 3-launch scan (rowptr also written
// to cursor, killing the D2D copy), cursor fill.
// ---------------------------------------------------------------------------
__global__ __launch_bounds__(256) void count_deg_kernel(
    const int* __restrict__ ei, int* __restrict__ deg, int E)
{
    const int e = blockIdx.x * 256 + threadIdx.x;
    if (e < E) atomicAdd(&deg[ei[E + e]], 1);
}

__global__ __launch_bounds__(256) void block_sum_kernel(
    const int* __restrict__ deg, int* __restrict__ bsum, int N)
{
    __shared__ int sm[256];
    const int idx = blockIdx.x * 256 + threadIdx.x;
    sm[threadIdx.x] = idx < N ? deg[idx] : 0;
    __syncthreads();
#pragma unroll
    for (int off = 128; off; off >>= 1) {
        if (threadIdx.x < off) sm[threadIdx.x] += sm[threadIdx.x + off];
        __syncthreads();
    }
    if (threadIdx.x == 0) bsum[blockIdx.x] = sm[0];
}

__global__ __launch_bounds__(256) void scan_bsums_kernel(
    int* __restrict__ bsum, int NB)
{
    __shared__ int sm[256];
    const int t = threadIdx.x;
    int v = t < NB ? bsum[t] : 0;
    sm[t] = v;
    __syncthreads();
#pragma unroll
    for (int off = 1; off < 256; off <<= 1) {
        const int u = (t >= off) ? sm[t - off] : 0;
        __syncthreads();
        sm[t] += u;
        __syncthreads();
    }
    if (t < NB) bsum[t] = sm[t] - v;   // exclusive
}

__global__ __launch_bounds__(256) void rowptr_kernel(
    const int* __restrict__ deg, const int* __restrict__ bsum,
    int* __restrict__ rowptr, int* __restrict__ cursor, int N)
{
    __shared__ int sm[256];
    const int t   = threadIdx.x;
    const int idx = blockIdx.x * 256 + t;
    const int v   = idx < N ? deg[idx] : 0;
    sm[t] = v;
    __syncthreads();
#pragma unroll
    for (int off = 1; off < 256; off <<= 1) {
        const int u = (t >= off) ? sm[t - off] : 0;
        __syncthreads();
        sm[t] += u;
        __syncthreads();
    }
    const int base = bsum[blockIdx.x];
    if (idx < N) {
        const int r = base + sm[t] - v;   // exclusive
        rowptr[idx] = r;
        cursor[idx] = r;
    }
    if (idx == N - 1) rowptr[N] = base + sm[t];
}

__global__ __launch_bounds__(256) void fill_csr_kernel(
    const int* __restrict__ ei, int* __restrict__ cursor,
    int* __restrict__ colsrc, int E)
{
    const int e = blockIdx.x * 256 + threadIdx.x;
    if (e >= E) return;
    const int d = ei[E + e];
    const int pos = atomicAdd(&cursor[d], 1);
    colsrc[pos] = ei[e];
}

// ---------------------------------------------------------------------------
// CSR aggregate (bf16 h gather, f32 accumulate), wave per dst node.
// a_src/a_dst arrive pre-scaled by LOG2E -> w = exp2(leaky(ee)), a single
// v_exp_f32. bf16 unpack via packed-uint AND/SHL. 4-wide edge unroll.
// MODE 0: concat + bias + ELU -> bf16 out[N,256].
// MODE 1: head-mean + bias + ELU -> bf16 out[N,64].
// ---------------------------------------------------------------------------
template <int MODE>
__global__ __launch_bounds__(256) void aggregate_csr_kernel(
    const int* __restrict__ rowptr, const int* __restrict__ colsrc,
    const ushort_t* __restrict__ hb, const float* __restrict__ a_src,
    const float* __restrict__ a_dst, const float* __restrict__ bias,
    ushort_t* __restrict__ out, int N)
{
    const int d    = (blockIdx.x * 256 + threadIdx.x) >> 6;
    const int lane = threadIdx.x & 63;
    if (d >= N) return;
    const int h  = lane >> 4;
    const int c0 = lane * 4;
    const float ad = a_dst[d * 4 + h];

    float4 acc = {0.f, 0.f, 0.f, 0.f};
    float  den = 0.f;

    const int beg = rowptr[d], end = rowptr[d + 1];
    int i = beg;
    for (; i + 4 <= end; i += 4) {
        int   sv[4];
        float av[4];
        uint2 qv[4];
#pragma unroll
        for (int j = 0; j < 4; ++j) sv[j] = colsrc[i + j];
#pragma unroll
        for (int j = 0; j < 4; ++j) av[j] = a_src[sv[j] * 4 + h];
#pragma unroll
        for (int j = 0; j < 4; ++j)
            qv[j] = *reinterpret_cast<const uint2*>(&hb[(size_t)sv[j] * HGAT_HC + c0]);
#pragma unroll
        for (int j = 0; j < 4; ++j) {
            float ee = av[j] + ad;
            ee = fmaxf(ee, 0.2f * ee);
            const float wgt = __builtin_amdgcn_exp2f(ee);
            acc.x += wgt * bflo(qv[j].x); acc.y += wgt * bfhi(qv[j].x);
            acc.z += wgt * bflo(qv[j].y); acc.w += wgt * bfhi(qv[j].y);
            den += wgt;
        }
    }
    for (; i < end; ++i) {
        const int s = colsrc[i];
        float ee = a_src[s * 4 + h] + ad;
        ee = fmaxf(ee, 0.2f * ee);
        const float wgt = __builtin_amdgcn_exp2f(ee);
        const uint2 q = *reinterpret_cast<const uint2*>(&hb[(size_t)s * HGAT_HC + c0]);
        acc.x += wgt * bflo(q.x); acc.y += wgt * bfhi(q.x);
        acc.z += wgt * bflo(q.y); acc.w += wgt * bfhi(q.y);
        den += wgt;
    }
    {   // self loop
        float ee = a_src[d * 4 + h] + ad;
        ee = fmaxf(ee, 0.2f * ee);
        const float wgt = __builtin_amdgcn_exp2f(ee);
        const uint2 q = *reinterpret_cast<const uint2*>(&hb[(size_t)d * HGAT_HC + c0]);
        acc.x += wgt * bflo(q.x); acc.y += wgt * bfhi(q.x);
        acc.z += wgt * bflo(q.y); acc.w += wgt * bfhi(q.y);
        den += wgt;
    }

    const float inv = 1.0f / den;
    float4 v = {acc.x * inv, acc.y * inv, acc.z * inv, acc.w * inv};

    if (MODE == 0) {
        v.x += bias[c0 + 0]; v.y += bias[c0 + 1];
        v.z += bias[c0 + 2]; v.w += bias[c0 + 3];
        v.x = v.x > 0.f ? v.x : expm1f(v.x);
        v.y = v.y > 0.f ? v.y : expm1f(v.y);
        v.z = v.z > 0.f ? v.z : expm1f(v.z);
        v.w = v.w > 0.f ? v.w : expm1f(v.w);
        ushort4 u;
        u.x = f2bf(v.x); u.y = f2bf(v.y); u.z = f2bf(v.z); u.w = f2bf(v.w);
        *reinterpret_cast<ushort4*>(&out[(size_t)d * HGAT_HC + c0]) = u;
    } else {
        v.x += __shfl_xor(v.x, 16); v.x += __shfl_xor(v.x, 32);
        v.y += __shfl_xor(v.y, 16); v.y += __shfl_xor(v.y, 32);
        v.z += __shfl_xor(v.z, 16); v.z += __shfl_xor(v.z, 32);
        v.w += __shfl_xor(v.w, 16); v.w += __shfl_xor(v.w, 32);
        if (lane < 16) {
            const int c = lane * 4;
            float4 r;
            r.x = 0.25f * v.x + bias[c + 0];
            r.y = 0.25f * v.y + bias[c + 1];
            r.z = 0.25f * v.z + bias[c + 2];
            r.w = 0.25f * v.w + bias[c + 3];
            r.x = r.x > 0.f ? r.x : expm1f(r.x);
            r.y = r.y > 0.f ? r.y : expm1f(r.y);
            r.z = r.z > 0.f ? r.z : expm1f(r.z);
            r.w = r.w > 0.f ? r.w : expm1f(r.w);
            ushort4 u;
            u.x = f2bf(r.x); u.y = f2bf(r.y); u.z = f2bf(r.z); u.w = f2bf(r.w);
            *reinterpret_cast<ushort4*>(&out[(size_t)d * HGAT_C + c]) = u;
        }
    }
}

// ---------------------------------------------------------------------------
// Two-stage segmented mean pool over sorted batch. No atomics.
// Stage A: 8 node-slices per graph -> partial[g*8+s][64].
// Stage B: combine 8 partials, divide by count.
// ---------------------------------------------------------------------------
__device__ __forceinline__ int lower_bound_batch(
    const int* __restrict__ batch, int N, int key)
{
    int lo = 0, hi = N;
    while (lo < hi) {
        const int mid = (lo + hi) >> 1;
        if (batch[mid] < key) lo = mid + 1; else hi = mid;
    }
    return lo;
}

__global__ __launch_bounds__(256) void pool_partial_kernel(
    const ushort_t* __restrict__ hfin, const int* __restrict__ batch,
    float* __restrict__ partial, int N)
{
    const int g   = blockIdx.x >> 3;
    const int s   = blockIdx.x & 7;
    const int t   = threadIdx.x;
    const int c   = t & 63;
    const int sub = t >> 6;   // 0..3

    const int beg = lower_bound_batch(batch, N, g);
    const int end = lower_bound_batch(batch, N, g + 1);
    const int len = end - beg;
    const int sl  = (len + 7) >> 3;
    const int sb  = beg + s * sl;
    const int se  = sb + sl < end ? sb + sl : end;

    float acc = 0.f;
    for (int n = sb + sub; n < se; n += 4)
        acc += bf2f(hfin[(size_t)n * HGAT_C + c]);

    __shared__ float sm[256];
    sm[t] = acc;
    __syncthreads();
    if (sub == 0)
        partial[(size_t)(g * 8 + s) * HGAT_C + c] =
            sm[c] + sm[64 + c] + sm[128 + c] + sm[192 + c];
}

__global__ __launch_bounds__(64) void pool_final_kernel(
    const float* __restrict__ partial, const int* __restrict__ batch,
    float* __restrict__ pooled, int N)
{
    const int g = blockIdx.x;
    const int c = threadIdx.x;
    const int beg = lower_bound_batch(batch, N, g);
    const int end = lower_bound_batch(batch, N, g + 1);
    float s = 0.f;
#pragma unroll
    for (int k = 0; k < 8; ++k)
        s += partial[(size_t)(g * 8 + k) * HGAT_C + c];
    pooled[g * HGAT_C + c] = s / fmaxf((float)(end - beg), 1.0f);
}

// ---------------------------------------------------------------------------
// Final: out[g,a] = pooled[g,:] @ Wa + ba
// ---------------------------------------------------------------------------
__global__ __launch_bounds__(256) void final_kernel(
    const float* __restrict__ pooled, const float* __restrict__ Wa,
    const float* __restrict__ ba, float* __restrict__ out)
{
    const int tid = blockIdx.x * 256 + threadIdx.x;
    if (tid >= NGRAPHS * NACT) return;
    const int g = tid >> 5, a = tid & 31;
    float s = 0.f;
#pragma unroll
    for (int c = 0; c < HGAT_C; ++c)
        s += pooled[g * HGAT_C + c] * Wa[c * NACT + a];
    out[tid] = s + ba[a];
}

// ---------------------------------------------------------------------------
extern "C" void kernel_launch(void* const* d_in, const int* in_sizes, int n_in,
                              void* d_out, int out_size, void* d_ws, size_t ws_size,
                              hipStream_t stream)
{
    const float* x     = (const float*)d_in[0];
    const int*   ei    = (const int*)d_in[1];
    const int*   batch = (const int*)d_in[2];
    const float* W1    = (const float*)d_in[5];
    const float* as1   = (const float*)d_in[6];
    const float* ad1   = (const float*)d_in[7];
    const float* b1    = (const float*)d_in[8];
    const float* W2    = (const float*)d_in[9];
    const float* as2   = (const float*)d_in[10];
    const float* ad2   = (const float*)d_in[11];
    const float* b2    = (const float*)d_in[12];
    const float* Wa    = (const float*)d_in[13];
    const float* ba    = (const float*)d_in[14];

    const int N = in_sizes[0] / FIN;
    const int E = in_sizes[1] / 2;

    char* ws = (char*)d_ws;
    size_t off = 0;
    auto alloc = [&](size_t bytes) -> void* {
        void* p = ws + off;
        off += (bytes + 255) & ~(size_t)255;
        return p;
    };
    ushort_t* hb      = (ushort_t*)alloc((size_t)N * HGAT_HC * 2);  // h (bf16)
    ushort_t* hpost   = (ushort_t*)alloc((size_t)N * HGAT_HC * 2);  // L1 out / hfin
    ushort_t* Wt1     = (ushort_t*)alloc((size_t)FIN * HGAT_HC * 2);
    ushort_t* Wt2     = (ushort_t*)alloc((size_t)HGAT_HC * HGAT_HC * 2);
    float*    a_src   = (float*)alloc((size_t)N * 4 * 4);
    float*    a_dst   = (float*)alloc((size_t)N * 4 * 4);
    int*      rowptr  = (int*)alloc((size_t)(N + 1) * 4);
    int*      colsrc  = (int*)alloc((size_t)E * 4);
    int*      deg     = (int*)alloc((size_t)N * 4);
    int*      cursor  = (int*)alloc((size_t)N * 4);
    int*      bsum    = (int*)alloc(256 * 4);
    float*    partial = (float*)alloc((size_t)NGRAPHS * 8 * HGAT_C * 4);
    float*    pooled  = (float*)alloc(NGRAPHS * HGAT_C * 4);
    ushort_t* hfin    = hpost;  // reuse: hpost consumed by gemm2 before agg<1> writes
    (void)ws_size; (void)n_in; (void)out_size;

    const int gemmBlocks     = (N + 127) / 128;
    const int edgeBlocks     = (E + 255) / 256;
    const int nodeWaveBlocks = (N + 3) / 4;
    const int NB             = (N + 255) / 256;   // <= 256 for N <= 65536

    // ---------------- CSR build (shared by both layers) ----------------
    hipMemsetAsync(deg, 0, (size_t)N * 4, stream);
    count_deg_kernel<<<edgeBlocks, 256, 0, stream>>>(ei, deg, E);
    block_sum_kernel<<<NB, 256, 0, stream>>>(deg, bsum, N);
    scan_bsums_kernel<<<1, 256, 0, stream>>>(bsum, NB);
    rowptr_kernel<<<NB, 256, 0, stream>>>(deg, bsum, rowptr, cursor, N);
    fill_csr_kernel<<<edgeBlocks, 256, 0, stream>>>(ei, cursor, colsrc, E);

    // ---------------- weight transpose/casts ----------------
    wcast_kernel<<<(FIN * HGAT_HC + 255) / 256, 256, 0, stream>>>(W1, Wt1, FIN);
    wcast_kernel<<<(HGAT_HC * HGAT_HC + 255) / 256, 256, 0, stream>>>(W2, Wt2, HGAT_HC);

    // ---------------- layer 1 (A = x f32, converted in-kernel) ----------------
    gemm_mfma_att_kernel<FIN, true><<<gemmBlocks, 256, 0, stream>>>(
        x, Wt1, hb, a_src, a_dst, as1, ad1, N);
    aggregate_csr_kernel<0><<<nodeWaveBlocks, 256, 0, stream>>>(
        rowptr, colsrc, hb, a_src, a_dst, b1, hpost, N);

    // ---------------- layer 2 ----------------
    gemm_mfma_att_kernel<HGAT_HC, false><<<gemmBlocks, 256, 0, stream>>>(
        hpost, Wt2, hb, a_src, a_dst, as2, ad2, N);
    aggregate_csr_kernel<1><<<nodeWaveBlocks, 256, 0, stream>>>(
        rowptr, colsrc, hb, a_src, a_dst, b2, hfin, N);

    // ---------------- pool + final ----------------
    pool_partial_kernel<<<NGRAPHS * 8, 256, 0, stream>>>(hfin, batch, partial, N);
    pool_final_kernel<<<NGRAPHS, 64, 0, stream>>>(partial, batch, pooled, N);
    final_kernel<<<(NGRAPHS * NACT + 255) / 256, 256, 0, stream>>>(
        pooled, Wa, ba, (float*)d_out);
}

// Round 10
// 315.438 us; speedup vs baseline: 7.4167x; 1.0002x over previous
//
#include <hip/hip_runtime.h>
#include <hip/hip_bf16.h>
#include <cstdint>
#include <cstddef>

#define FIN      128
#define HGAT_H   4
#define HGAT_C   64
#define HGAT_HC  256
#define NGRAPHS  64
#define NACT     32
#define LOG2E    1.4426950408889634f

typedef unsigned int   uint32;
typedef unsigned short ushort_t;

using short8 = __attribute__((ext_vector_type(8))) short;
using u16x8  = __attribute__((ext_vector_type(8))) ushort_t;
using f32x4  = __attribute__((ext_vector_type(4))) float;
using f32x2  = __attribute__((ext_vector_type(2))) float;

__device__ __forceinline__ float bf2f(ushort_t u) {
    return __uint_as_float(((uint32)u) << 16);
}
__device__ __forceinline__ float bflo(uint32 q) {
    return __uint_as_float(q << 16);
}
__device__ __forceinline__ float bfhi(uint32 q) {
    return __uint_as_float(q & 0xFFFF0000u);
}
__device__ __forceinline__ ushort_t f2bf(float f) {
    __hip_bfloat16 h = __float2bfloat16(f);   // RNE
    return *reinterpret_cast<ushort_t*>(&h);
}

// ---------------------------------------------------------------------------
// Both weight transposes/casts in one launch.
// W[K][256] f32 -> Wt[256][K] bf16, for W1 (K=128) and W2 (K=256).
// ---------------------------------------------------------------------------
__global__ __launch_bounds__(256) void wcast2_kernel(
    const float* __restrict__ W1, const float* __restrict__ W2,
    ushort_t* __restrict__ Wt1, ushort_t* __restrict__ Wt2)
{
    const int idx = blockIdx.x * 256 + threadIdx.x;
    const int n1 = FIN * HGAT_HC;          // 32768
    const int n2 = HGAT_HC * HGAT_HC;      // 65536
    if (idx < n1) {
        const int k = idx >> 8, c = idx & 255;
        Wt1[(size_t)c * FIN + k] = f2bf(W1[idx]);
    } else if (idx < n1 + n2) {
        const int j = idx - n1;
        const int k = j >> 8, c = j & 255;
        Wt2[(size_t)c * HGAT_HC + k] = f2bf(W2[j]);
    }
}

// ---------------------------------------------------------------------------
// MFMA GEMM + attention epilogue.  C[M,256] = A[M,K] @ Wt^T.
// Block = 64 rows, 4 waves; wave w owns rows [w*16, +16). A frags in
// registers for the whole kernel. Per head, the 64xK B panel lives in LDS
// (stride K+8); the NEXT head's panel is register-prefetched during the
// current head's MFMA loop (global latency hides under compute).
// 782 blocks -> ~3 blocks/CU (occupancy fix vs 391-block version).
// Epilogue: attention dots (pre-scaled by LOG2E) via 16-lane shfl + bf16 C.
// mfma_f32_16x16x32_bf16 D map: col=lane&15, row=(lane>>4)*4+reg.
// ---------------------------------------------------------------------------
template <int K, bool AF32>
__global__ __launch_bounds__(256) void gemm_mfma_att_kernel(
    const void* __restrict__ Av, const ushort_t* __restrict__ Bt,
    ushort_t* __restrict__ Cb, float* __restrict__ a_src,
    float* __restrict__ a_dst, const float* __restrict__ att_s,
    const float* __restrict__ att_d, int M)
{
    constexpr int KK   = K / 32;   // mfma k-steps
    constexpr int NPF  = K / 32;   // prefetch chunks (K/4 ushorts = K/32 u16x8)
    constexpr int BSTR = K + 8;
    __shared__ ushort_t Bs[64 * BSTR];

    const int t  = threadIdx.x;
    const int w  = t >> 6;
    const int l  = t & 63;
    const int lg = l >> 4;
    const int lr = l & 15;
    const int rowbase = blockIdx.x * 64 + w * 16;

    // staging geometry: thread t handles row (t&63), K/4 ushorts at cbase
    const int srow  = t & 63;
    const int cbase = (t >> 6) * (K / 4);

    // ---- A fragments: registers for the whole kernel (A read once)
    short8 af[KK];
    {
        const int arow = rowbase + lr;
        const int gr   = arow < M ? arow : M - 1;
        if (AF32) {
            const float* Ap = (const float*)Av + (size_t)gr * K;
#pragma unroll
            for (int kk = 0; kk < KK; ++kk) {
                const float4 v0 = *reinterpret_cast<const float4*>(Ap + kk * 32 + lg * 8);
                const float4 v1 = *reinterpret_cast<const float4*>(Ap + kk * 32 + lg * 8 + 4);
                short8 s;
                s[0] = (short)f2bf(v0.x); s[1] = (short)f2bf(v0.y);
                s[2] = (short)f2bf(v0.z); s[3] = (short)f2bf(v0.w);
                s[4] = (short)f2bf(v1.x); s[5] = (short)f2bf(v1.y);
                s[6] = (short)f2bf(v1.z); s[7] = (short)f2bf(v1.w);
                af[kk] = s;
            }
        } else {
            const ushort_t* Ap = (const ushort_t*)Av + (size_t)gr * K;
#pragma unroll
            for (int kk = 0; kk < KK; ++kk)
                af[kk] = *reinterpret_cast<const short8*>(Ap + kk * 32 + lg * 8);
        }
    }

    // ---- prologue: stage head 0 panel
    u16x8 pf[NPF];
    {
        const ushort_t* src = Bt + (size_t)srow * K + cbase;   // head 0
#pragma unroll
        for (int j = 0; j < NPF; ++j)
            pf[j] = *reinterpret_cast<const u16x8*>(src + j * 8);
        ushort_t* dst = &Bs[srow * BSTR + cbase];
#pragma unroll
        for (int j = 0; j < NPF; ++j)
            *reinterpret_cast<u16x8*>(dst + j * 8) = pf[j];
    }

#pragma unroll
    for (int head = 0; head < HGAT_H; ++head) {
        __syncthreads();   // Bs (this head) visible to all

        if (head < HGAT_H - 1) {   // issue next head's loads now
            const ushort_t* src =
                Bt + ((size_t)(head + 1) * 64 + srow) * K + cbase;
#pragma unroll
            for (int j = 0; j < NPF; ++j)
                pf[j] = *reinterpret_cast<const u16x8*>(src + j * 8);
        }

        f32x4 acc[4];
#pragma unroll
        for (int ct = 0; ct < 4; ++ct) acc[ct] = {0.f, 0.f, 0.f, 0.f};

#pragma unroll
        for (int kk = 0; kk < KK; ++kk) {
            short8 bfr[4];
#pragma unroll
            for (int ct = 0; ct < 4; ++ct)
                bfr[ct] = *reinterpret_cast<const short8*>(
                    &Bs[(ct * 16 + lr) * BSTR + kk * 32 + lg * 8]);
#pragma unroll
            for (int ct = 0; ct < 4; ++ct)
                acc[ct] = __builtin_amdgcn_mfma_f32_16x16x32_bf16(
                    af[kk], bfr[ct], acc[ct], 0, 0, 0);
        }

        // epilogue: attention dots + bf16 C store for this head
        const int n0 = head * 64;
        float atsv[4], atdv[4];
#pragma unroll
        for (int ct = 0; ct < 4; ++ct) {
            atsv[ct] = att_s[n0 + ct * 16 + lr];
            atdv[ct] = att_d[n0 + ct * 16 + lr];
        }
#pragma unroll
        for (int reg = 0; reg < 4; ++reg) {
            const int gm = rowbase + lg * 4 + reg;
            float s = 0.f, d = 0.f;
#pragma unroll
            for (int ct = 0; ct < 4; ++ct) {
                const float v = acc[ct][reg];
                s += v * atsv[ct];
                d += v * atdv[ct];
            }
#pragma unroll
            for (int off = 1; off < 16; off <<= 1) {
                s += __shfl_xor(s, off);
                d += __shfl_xor(d, off);
            }
            if (gm < M) {
#pragma unroll
                for (int ct = 0; ct < 4; ++ct)
                    Cb[(size_t)gm * HGAT_HC + n0 + ct * 16 + lr] =
                        f2bf(acc[ct][reg]);
                if (lr == 0) {
                    a_src[gm * 4 + head] = s * LOG2E;
                    a_dst[gm * 4 + head] = d * LOG2E;
                }
            }
        }

        __syncthreads();   // all waves done reading Bs
        if (head < HGAT_H - 1) {   // commit prefetched panel
            ushort_t* dst = &Bs[srow * BSTR + cbase];
#pragma unroll
            for (int j = 0; j < NPF; ++j)
                *reinterpret_cast<u16x8*>(dst + j * 8) = pf[j];
        }
    }
}

// ---------------------------------------------------------------------------
// CSR build: degree count, hierarchical scan, cursor fill.
// ---------------------------------------------------------------------------
__global__ __launch_bounds__(256) void count_deg_kernel(
    const int* __restrict__ ei, int* __restrict__ deg, int E)
{
    const int e = blockIdx.x * 256 + threadIdx.x;
    if (e < E) atomicAdd(&deg[ei[E + e]], 1);
}

__global__ __launch_bounds__(256) void block_sum_kernel(
    const int* __restrict__ deg, int* __restrict__ bsum, int N)
{
    __shared__ int sm[256];
    const int idx = blockIdx.x * 256 + threadIdx.x;
    sm[threadIdx.x] = idx < N ? deg[idx] : 0;
    __syncthreads();
#pragma unroll
    for (int off = 128; off; off >>= 1) {
        if (threadIdx.x < off) sm[threadIdx.x] += sm[threadIdx.x + off];
        __syncthreads();
    }
    if (threadIdx.x == 0) bsum[blockIdx.x] = sm[0];
}

__global__ __launch_bounds__(256) void scan_bsums_kernel(
    int* __restrict__ bsum, int NB)
{
    __shared__ int sm[256];
    const int t = threadIdx.x;
    int v = t < NB ? bsum[t] : 0;
    sm[t] = v;
    __syncthreads();
#pragma unroll
    for (int off = 1; off < 256; off <<= 1) {
        const int u = (t >= off) ? sm[t - off] : 0;
        __syncthreads();
        sm[t] += u;
        __syncthreads();
    }
    if (t < NB) bsum[t] = sm[t] - v;   // exclusive
}

__global__ __launch_bounds__(256) void rowptr_kernel(
    const int* __restrict__ deg, const int* __restrict__ bsum,
    int* __restrict__ rowptr, int* __restrict__ cursor, int N)
{
    __shared__ int sm[256];
    const int t   = threadIdx.x;
    const int idx = blockIdx.x * 256 + t;
    const int v   = idx < N ? deg[idx] : 0;
    sm[t] = v;
    __syncthreads();
#pragma unroll
    for (int off = 1; off < 256; off <<= 1) {
        const int u = (t >= off) ? sm[t - off] : 0;
        __syncthreads();
        sm[t] += u;
        __syncthreads();
    }
    const int base = bsum[blockIdx.x];
    if (idx < N) {
        const int r = base + sm[t] - v;
        rowptr[idx] = r;
        cursor[idx] = r;
    }
    if (idx == N - 1) rowptr[N] = base + sm[t];
}

__global__ __launch_bounds__(256) void fill_csr_kernel(
    const int* __restrict__ ei, int* __restrict__ cursor,
    int* __restrict__ colsrc, int E)
{
    const int e = blockIdx.x * 256 + threadIdx.x;
    if (e >= E) return;
    const int d = ei[E + e];
    const int pos = atomicAdd(&cursor[d], 1);
    colsrc[pos] = ei[e];
}

// ---------------------------------------------------------------------------
// CSR aggregate (bf16 h gather, packed f32 accumulate), wave per dst node.
// a_src/a_dst pre-scaled by LOG2E -> single v_exp_f32 per edge. f32x2
// accumulators invite v_pk_fma_f32. 4-wide edge unroll for MLP.
// MODE 0: concat + bias + ELU -> bf16 out[N,256].
// MODE 1: head-mean + bias + ELU -> bf16 out[N,64].
// ---------------------------------------------------------------------------
template <int MODE>
__global__ __launch_bounds__(256) void aggregate_csr_kernel(
    const int* __restrict__ rowptr, const int* __restrict__ colsrc,
    const ushort_t* __restrict__ hb, const float* __restrict__ a_src,
    const float* __restrict__ a_dst, const float* __restrict__ bias,
    ushort_t* __restrict__ out, int N)
{
    const int d    = (blockIdx.x * 256 + threadIdx.x) >> 6;
    const int lane = threadIdx.x & 63;
    if (d >= N) return;
    const int h  = lane >> 4;
    const int c0 = lane * 4;
    const float ad = a_dst[d * 4 + h];

    f32x2 acc01 = {0.f, 0.f}, acc23 = {0.f, 0.f};
    float den = 0.f;

    const int beg = rowptr[d], end = rowptr[d + 1];
    int i = beg;
    for (; i + 4 <= end; i += 4) {
        int   sv[4];
        float av[4];
        uint2 qv[4];
#pragma unroll
        for (int j = 0; j < 4; ++j) sv[j] = colsrc[i + j];
#pragma unroll
        for (int j = 0; j < 4; ++j) av[j] = a_src[sv[j] * 4 + h];
#pragma unroll
        for (int j = 0; j < 4; ++j)
            qv[j] = *reinterpret_cast<const uint2*>(&hb[(size_t)sv[j] * HGAT_HC + c0]);
#pragma unroll
        for (int j = 0; j < 4; ++j) {
            float ee = av[j] + ad;
            ee = fmaxf(ee, 0.2f * ee);
            const float wgt = __builtin_amdgcn_exp2f(ee);
            const f32x2 w2 = {wgt, wgt};
            const f32x2 p01 = {bflo(qv[j].x), bfhi(qv[j].x)};
            const f32x2 p23 = {bflo(qv[j].y), bfhi(qv[j].y)};
            acc01 += w2 * p01;
            acc23 += w2 * p23;
            den += wgt;
        }
    }
    for (; i < end; ++i) {
        const int s = colsrc[i];
        float ee = a_src[s * 4 + h] + ad;
        ee = fmaxf(ee, 0.2f * ee);
        const float wgt = __builtin_amdgcn_exp2f(ee);
        const uint2 q = *reinterpret_cast<const uint2*>(&hb[(size_t)s * HGAT_HC + c0]);
        const f32x2 w2 = {wgt, wgt};
        const f32x2 p01 = {bflo(q.x), bfhi(q.x)};
        const f32x2 p23 = {bflo(q.y), bfhi(q.y)};
        acc01 += w2 * p01;
        acc23 += w2 * p23;
        den += wgt;
    }
    {   // self loop
        float ee = a_src[d * 4 + h] + ad;
        ee = fmaxf(ee, 0.2f * ee);
        const float wgt = __builtin_amdgcn_exp2f(ee);
        const uint2 q = *reinterpret_cast<const uint2*>(&hb[(size_t)d * HGAT_HC + c0]);
        const f32x2 w2 = {wgt, wgt};
        const f32x2 p01 = {bflo(q.x), bfhi(q.x)};
        const f32x2 p23 = {bflo(q.y), bfhi(q.y)};
        acc01 += w2 * p01;
        acc23 += w2 * p23;
        den += wgt;
    }

    const float inv = 1.0f / den;
    float4 v = {acc01.x * inv, acc01.y * inv, acc23.x * inv, acc23.y * inv};

    if (MODE == 0) {
        v.x += bias[c0 + 0]; v.y += bias[c0 + 1];
        v.z += bias[c0 + 2]; v.w += bias[c0 + 3];
        v.x = v.x > 0.f ? v.x : expm1f(v.x);
        v.y = v.y > 0.f ? v.y : expm1f(v.y);
        v.z = v.z > 0.f ? v.z : expm1f(v.z);
        v.w = v.w > 0.f ? v.w : expm1f(v.w);
        ushort4 u;
        u.x = f2bf(v.x); u.y = f2bf(v.y); u.z = f2bf(v.z); u.w = f2bf(v.w);
        *reinterpret_cast<ushort4*>(&out[(size_t)d * HGAT_HC + c0]) = u;
    } else {
        v.x += __shfl_xor(v.x, 16); v.x += __shfl_xor(v.x, 32);
        v.y += __shfl_xor(v.y, 16); v.y += __shfl_xor(v.y, 32);
        v.z += __shfl_xor(v.z, 16); v.z += __shfl_xor(v.z, 32);
        v.w += __shfl_xor(v.w, 16); v.w += __shfl_xor(v.w, 32);
        if (lane < 16) {
            const int c = lane * 4;
            float4 r;
            r.x = 0.25f * v.x + bias[c + 0];
            r.y = 0.25f * v.y + bias[c + 1];
            r.z = 0.25f * v.z + bias[c + 2];
            r.w = 0.25f * v.w + bias[c + 3];
            r.x = r.x > 0.f ? r.x : expm1f(r.x);
            r.y = r.y > 0.f ? r.y : expm1f(r.y);
            r.z = r.z > 0.f ? r.z : expm1f(r.z);
            r.w = r.w > 0.f ? r.w : expm1f(r.w);
            ushort4 u;
            u.x = f2bf(r.x); u.y = f2bf(r.y); u.z = f2bf(r.z); u.w = f2bf(r.w);
            *reinterpret_cast<ushort4*>(&out[(size_t)d * HGAT_C + c]) = u;
        }
    }
}

// ---------------------------------------------------------------------------
// Pool stage A: 8 node-slices per graph -> partial sums.
// ---------------------------------------------------------------------------
__device__ __forceinline__ int lower_bound_batch(
    const int* __restrict__ batch, int N, int key)
{
    int lo = 0, hi = N;
    while (lo < hi) {
        const int mid = (lo + hi) >> 1;
        if (batch[mid] < key) lo = mid + 1; else hi = mid;
    }
    return lo;
}

__global__ __launch_bounds__(256) void pool_partial_kernel(
    const ushort_t* __restrict__ hfin, const int* __restrict__ batch,
    float* __restrict__ partial, int N)
{
    const int g   = blockIdx.x >> 3;
    const int s   = blockIdx.x & 7;
    const int t   = threadIdx.x;
    const int c   = t & 63;
    const int sub = t >> 6;

    const int beg = lower_bound_batch(batch, N, g);
    const int end = lower_bound_batch(batch, N, g + 1);
    const int len = end - beg;
    const int sl  = (len + 7) >> 3;
    const int sb  = beg + s * sl;
    const int se  = sb + sl < end ? sb + sl : end;

    float acc = 0.f;
    for (int n = sb + sub; n < se; n += 4)
        acc += bf2f(hfin[(size_t)n * HGAT_C + c]);

    __shared__ float sm[256];
    sm[t] = acc;
    __syncthreads();
    if (sub == 0)
        partial[(size_t)(g * 8 + s) * HGAT_C + c] =
            sm[c] + sm[64 + c] + sm[128 + c] + sm[192 + c];
}

// ---------------------------------------------------------------------------
// Pool stage B fused with final linear: one block per graph.
// ---------------------------------------------------------------------------
__global__ __launch_bounds__(64) void pool_final_fused_kernel(
    const float* __restrict__ partial, const int* __restrict__ batch,
    const float* __restrict__ Wa, const float* __restrict__ ba,
    float* __restrict__ out, int N)
{
    const int g = blockIdx.x;
    const int c = threadIdx.x;
    const int beg = lower_bound_batch(batch, N, g);
    const int end = lower_bound_batch(batch, N, g + 1);
    float s = 0.f;
#pragma unroll
    for (int k = 0; k < 8; ++k)
        s += partial[(size_t)(g * 8 + k) * HGAT_C + c];
    s /= fmaxf((float)(end - beg), 1.0f);

    __shared__ float pr[HGAT_C];
    pr[c] = s;
    __syncthreads();
    if (c < NACT) {
        float o = ba[c];
#pragma unroll
        for (int cc = 0; cc < HGAT_C; ++cc)
            o += pr[cc] * Wa[cc * NACT + c];
        out[g * NACT + c] = o;
    }
}

// ---------------------------------------------------------------------------
extern "C" void kernel_launch(void* const* d_in, const int* in_sizes, int n_in,
                              void* d_out, int out_size, void* d_ws, size_t ws_size,
                              hipStream_t stream)
{
    const float* x     = (const float*)d_in[0];
    const int*   ei    = (const int*)d_in[1];
    const int*   batch = (const int*)d_in[2];
    const float* W1    = (const float*)d_in[5];
    const float* as1   = (const float*)d_in[6];
    const float* ad1   = (const float*)d_in[7];
    const float* b1    = (const float*)d_in[8];
    const float* W2    = (const float*)d_in[9];
    const float* as2   = (const float*)d_in[10];
    const float* ad2   = (const float*)d_in[11];
    const float* b2    = (const float*)d_in[12];
    const float* Wa    = (const float*)d_in[13];
    const float* ba    = (const float*)d_in[14];

    const int N = in_sizes[0] / FIN;
    const int E = in_sizes[1] / 2;

    char* ws = (char*)d_ws;
    size_t off = 0;
    auto alloc = [&](size_t bytes) -> void* {
        void* p = ws + off;
        off += (bytes + 255) & ~(size_t)255;
        return p;
    };
    ushort_t* hb      = (ushort_t*)alloc((size_t)N * HGAT_HC * 2);
    ushort_t* hpost   = (ushort_t*)alloc((size_t)N * HGAT_HC * 2);
    ushort_t* Wt1     = (ushort_t*)alloc((size_t)FIN * HGAT_HC * 2);
    ushort_t* Wt2     = (ushort_t*)alloc((size_t)HGAT_HC * HGAT_HC * 2);
    float*    a_src   = (float*)alloc((size_t)N * 4 * 4);
    float*    a_dst   = (float*)alloc((size_t)N * 4 * 4);
    int*      rowptr  = (int*)alloc((size_t)(N + 1) * 4);
    int*      colsrc  = (int*)alloc((size_t)E * 4);
    int*      deg     = (int*)alloc((size_t)N * 4);
    int*      cursor  = (int*)alloc((size_t)N * 4);
    int*      bsum    = (int*)alloc(256 * 4);
    float*    partial = (float*)alloc((size_t)NGRAPHS * 8 * HGAT_C * 4);
    ushort_t* hfin    = hpost;
    (void)ws_size; (void)n_in; (void)out_size;

    const int gemmBlocks     = (N + 63) / 64;
    const int edgeBlocks     = (E + 255) / 256;
    const int nodeWaveBlocks = (N + 3) / 4;
    const int NB             = (N + 255) / 256;

    // ---------------- CSR build ----------------
    hipMemsetAsync(deg, 0, (size_t)N * 4, stream);
    count_deg_kernel<<<edgeBlocks, 256, 0, stream>>>(ei, deg, E);
    block_sum_kernel<<<NB, 256, 0, stream>>>(deg, bsum, N);
    scan_bsums_kernel<<<1, 256, 0, stream>>>(bsum, NB);
    rowptr_kernel<<<NB, 256, 0, stream>>>(deg, bsum, rowptr, cursor, N);
    fill_csr_kernel<<<edgeBlocks, 256, 0, stream>>>(ei, cursor, colsrc, E);

    // ---------------- weight transpose/cast (single launch) ----------------
    wcast2_kernel<<<(FIN * HGAT_HC + HGAT_HC * HGAT_HC + 255) / 256, 256, 0, stream>>>(
        W1, W2, Wt1, Wt2);

    // ---------------- layer 1 ----------------
    gemm_mfma_att_kernel<FIN, true><<<gemmBlocks, 256, 0, stream>>>(
        x, Wt1, hb, a_src, a_dst, as1, ad1, N);
    aggregate_csr_kernel<0><<<nodeWaveBlocks, 256, 0, stream>>>(
        rowptr, colsrc, hb, a_src, a_dst, b1, hpost, N);

    // ---------------- layer 2 ----------------
    gemm_mfma_att_kernel<HGAT_HC, false><<<gemmBlocks, 256, 0, stream>>>(
        hpost, Wt2, hb, a_src, a_dst, as2, ad2, N);
    aggregate_csr_kernel<1><<<nodeWaveBlocks, 256, 0, stream>>>(
        rowptr, colsrc, hb, a_src, a_dst, b2, hfin, N);

    // ---------------- pool + final ----------------
    pool_partial_kernel<<<NGRAPHS * 8, 256, 0, stream>>>(hfin, batch, partial, N);
    pool_final_fused_kernel<<<NGRAPHS, 64, 0, stream>>>(
        partial, batch, Wa, ba, (float*)d_out, N);
}